// Round 16
// baseline (106.595 us; speedup 1.0000x reference)
//
#include <hip/hip_runtime.h>

#define BB 16
#define TT 30
#define NSEL 5
#define NCLS 10

typedef __attribute__((ext_vector_type(8))) short short8_t;
typedef __attribute__((ext_vector_type(4))) float f32x4;

__device__ inline unsigned short f2bf(float x) {
    unsigned int u = __float_as_uint(x);
    unsigned int r = u + 0x7FFFu + ((u >> 16) & 1u);
    return (unsigned short)(r >> 16);
}

// ---------------- prep_all: blocks 0..191 skim resize (float4); 192..479 weight pack + zeroing
__global__ __launch_bounds__(256) void prep_all(const float* __restrict__ ff64,
                                                const float* __restrict__ w2,
                                                const float* __restrict__ w1,
                                                float* __restrict__ skim_res,
                                                unsigned short* __restrict__ wpk,
                                                unsigned short* __restrict__ wpk1,
                                                float* __restrict__ gsum,
                                                float* __restrict__ gsum2) {
    int bid = blockIdx.x;
    int t = threadIdx.x;
    if (bid < 192) {
        int gid = bid * 256 + t;
        int xg = gid & 15;
        int oy = (gid >> 4) & 63;
        int bc = gid >> 10;
        int c = bc % 3, b = bc / 3;
        int ox0 = xg * 4;
        float sample = 30.f * (float)oy + 14.5f;
        int jlo = max(0, 30 * oy - 16);
        int jhi = min(TT * 64 - 1, 30 * oy + 45);
        float ax = 0.f, ay = 0.f, az = 0.f, aw = 0.f, ws = 0.f;
        for (int j = jlo; j <= jhi; ++j) {
            float w = fmaxf(0.f, 1.f - fabsf(sample - (float)j) * (1.f / 30.f));
            int tt = j >> 6, y = j & 63;
            const float4 v = *(const float4*)&ff64[(((b * TT + tt) * 3 + c) << 12) + (y << 6) + ox0];
            ax += w * v.x; ay += w * v.y; az += w * v.z; aw += w * v.w;
            ws += w;
        }
        float inv = 1.f / ws;
        float4 r; r.x = ax * inv; r.y = ay * inv; r.z = az * inv; r.w = aw * inv;
        *(float4*)&skim_res[(((b * 3 + c) << 6) + oy) * 64 + ox0] = r;
    } else {
        int i = (bid - 192) * 256 + t;
        if (i < BB * 128) gsum[i] = 0.f;
        if (i < BB * 64) gsum2[i] = 0.f;
        if (i < 4 * 64 * 8) {
            int j = i & 7;
            int lane = (i >> 3) & 63;
            int af = i >> 9;
            int oc = af * 16 + (lane & 15);
            int k = ((lane >> 4) << 3) + j;
            wpk1[i] = (k < 27) ? f2bf(w1[oc * 27 + k]) : (unsigned short)0;
        }
        if (i < 9 * 2 * 8 * 64 * 8) {
            int j = i & 7;
            int lane = (i >> 3) & 63;
            int af = (i >> 9) & 7;
            int h = (i >> 12) & 1;
            int tap = i >> 13;
            int oc = af * 16 + (lane & 15);
            int ic = h * 32 + ((lane >> 4) << 3) + j;
            int ky = tap / 3, kx = tap % 3;
            wpk[i] = f2bf(w2[((size_t)(oc * 64 + ic)) * 9 + ky * 3 + kx]);
        }
    }
}

// ---------------- skim conv1 tiled fp32 (exact): [16,3,64,64] -> [16,32,32,32]
__global__ __launch_bounds__(256) void sconv1_t(const float* __restrict__ in,
                                                const float* __restrict__ w,
                                                float* __restrict__ h1) {
    int oy = blockIdx.x & 31;
    int b  = blockIdx.x >> 5;
    int t = threadIdx.x;
    int oc = t & 31;
    int oxg = t >> 5;

    __shared__ float in_s[3][3][64];
    __shared__ float w_s[27][32];

    int iy0 = oy * 2;
    for (int u = t; u < 576; u += 256) {
        int ix = u & 63;
        int ry = (u >> 6) % 3;
        int ic = u / 192;
        int iy = iy0 + ry;
        in_s[ic][ry][ix] = (iy < 64) ? in[((b * 3 + ic) * 64 + iy) * 64 + ix] : 0.f;
    }
    for (int u = t; u < 864; u += 256) {
        int oc2 = u & 31;
        int k = u >> 5;
        w_s[k][oc2] = w[oc2 * 27 + k];
    }
    __syncthreads();

    float acc[4] = {0.f, 0.f, 0.f, 0.f};
    #pragma unroll
    for (int ic = 0; ic < 3; ++ic) {
        #pragma unroll
        for (int ky = 0; ky < 3; ++ky) {
            float xv[9];
            #pragma unroll
            for (int i = 0; i < 9; ++i) {
                int ix = oxg * 8 + i;
                xv[i] = (ix < 64) ? in_s[ic][ky][ix] : 0.f;
            }
            #pragma unroll
            for (int kx = 0; kx < 3; ++kx) {
                float wv = w_s[ic * 9 + ky * 3 + kx][oc];
                #pragma unroll
                for (int p = 0; p < 4; ++p) acc[p] += wv * xv[2 * p + kx];
            }
        }
    }
    float* op = &h1[((b * 32 + oc) * 32 + oy) * 32 + oxg * 4];
    #pragma unroll
    for (int p = 0; p < 4; ++p) op[p] = fmaxf(acc[p], 0.f);
}

// ---------------- skim conv2 tiled fp32 (exact) fused relu+mean: [16,32,32,32] -> gsum2[16,64]
__global__ __launch_bounds__(256) void sconv2_t(const float* __restrict__ h1,
                                                const float* __restrict__ w,
                                                float* __restrict__ gsum2) {
    int oy = blockIdx.x;
    int ocg = blockIdx.y;
    int b = blockIdx.z;
    int t = threadIdx.x;
    int oc = t & 31;
    int oxg = t >> 5;

    __shared__ float in_s[32][3][32];
    __shared__ float w_s[288 * 32];   // [R=ic*9+k][oc ^ (R&31)]

    int iy0 = oy * 2;
    for (int u = t; u < 32 * 3 * 32; u += 256) {
        int ix = u & 31;
        int ry = (u >> 5) % 3;
        int ic = u / 96;
        int iy = iy0 + ry;
        in_s[ic][ry][ix] = (iy < 32) ? h1[((b * 32 + ic) * 32 + iy) * 32 + ix] : 0.f;
    }
    for (int u = t; u < 9216; u += 256) {
        int ocl = u / 288;
        int rem = u - ocl * 288;
        w_s[rem * 32 + (ocl ^ (rem & 31))] = w[(ocg * 32 + ocl) * 288 + rem];
    }
    __syncthreads();

    float acc0 = 0.f, acc1 = 0.f;
    for (int ic = 0; ic < 32; ++ic) {
        #pragma unroll
        for (int ky = 0; ky < 3; ++ky) {
            float xv[5];
            #pragma unroll
            for (int i = 0; i < 5; ++i) {
                int ix = oxg * 4 + i;
                xv[i] = (ix < 32) ? in_s[ic][ky][ix] : 0.f;
            }
            #pragma unroll
            for (int kx = 0; kx < 3; ++kx) {
                int R = ic * 9 + ky * 3 + kx;
                float wv = w_s[R * 32 + (oc ^ (R & 31))];
                acc0 += wv * xv[kx];
                acc1 += wv * xv[2 + kx];
            }
        }
    }
    float ps = fmaxf(acc0, 0.f) + fmaxf(acc1, 0.f);
    ps += __shfl_xor(ps, 32);
    if ((t & 32) == 0) atomicAdd(&gsum2[b * 64 + ocg * 32 + oc], ps);
}

// ---------------- eval conv1 FUSED: policy/top-5 + gather-resize staging + MFMA
__global__ __launch_bounds__(256) void conv1_fused(const float* __restrict__ ff224,
                                                   const float* __restrict__ gsum2,
                                                   const float* __restrict__ pol_w,
                                                   const float* __restrict__ pol_b,
                                                   const unsigned short* __restrict__ wpk1,
                                                   unsigned short* __restrict__ outcl) {
    int oxT = blockIdx.x;            // 0..6
    int oyT = blockIdx.y;            // 0..27
    int b = blockIdx.z;
    int t = threadIdx.x;
    int w = t >> 6;                  // wave -> oy = oyT*4 + w
    int lane = t & 63;
    int col = lane & 15;
    int kq = lane >> 4;

    __shared__ float fea[64];
    __shared__ float logits[TT];
    __shared__ unsigned char insel[TT];
    __shared__ int sidx[NSEL];
    __shared__ unsigned short in_s[3][9][36];

    if (t < 64) fea[t] = fmaxf(gsum2[b * 64 + t] * (1.f / 256.f), 0.f);
    __syncthreads();
    if (t < TT) {
        float l = pol_b[t];
        for (int cc = 0; cc < 64; ++cc) l += fea[cc] * pol_w[cc * TT + t];
        logits[t] = l;
    }
    __syncthreads();
    if (t < TT) {
        float li = logits[t];
        int rank = 0;
        for (int j = 0; j < TT; ++j) {
            float lj = logits[j];
            rank += (lj > li) || (lj == li && j < t);
        }
        insel[t] = (rank < NSEL) ? 1 : 0;
    }
    __syncthreads();
    if (t < TT && insel[t]) {
        int pos = 0;
        for (int j = 0; j < t; ++j) pos += insel[j];
        sidx[pos] = t;
    }
    __syncthreads();

    int iy0 = oyT * 8, ix0 = oxT * 32;
    if (t < 243) {
        int rx0 = (t % 9) * 4;
        int ry = (t / 9) % 9;
        int ic = t / 81;
        int oy = iy0 + ry;
        int ox0 = ix0 + rx0;
        ushort4 v4 = {0, 0, 0, 0};
        if (oy < 224 && ox0 < 224) {
            float sample = 5.f * (float)oy + 2.f;
            int j0 = 5 * oy - 3;
            float ax = 0.f, ay = 0.f, az = 0.f, aw = 0.f, wsum = 0.f;
            #pragma unroll
            for (int dj = 0; dj < 11; ++dj) {
                int j = j0 + dj;
                float wt = (j >= 0 && j < NSEL * 224)
                               ? fmaxf(0.f, 1.f - fabsf(sample - (float)j) * 0.2f) : 0.f;
                int jc = min(max(j, 0), NSEL * 224 - 1);
                int s = jc / 224, y = jc % 224;
                int tf = sidx[s];
                const float4 v = *(const float4*)&ff224[((size_t)((b * TT + tf) * 3 + ic) * 224 + y) * 224 + ox0];
                ax += wt * v.x; ay += wt * v.y; az += wt * v.z; aw += wt * v.w;
                wsum += wt;
            }
            float inv = 1.f / wsum;
            v4.x = f2bf(ax * inv); v4.y = f2bf(ay * inv);
            v4.z = f2bf(az * inv); v4.w = f2bf(aw * inv);
        }
        *(ushort4*)&in_s[ic][ry][rx0] = v4;
    }
    __syncthreads();

    short8_t a[4];
    #pragma unroll
    for (int af = 0; af < 4; ++af)
        a[af] = *(const short8_t*)&wpk1[((af << 6) + lane) << 3];

    unsigned int bw[4];
    #pragma unroll
    for (int jj = 0; jj < 4; ++jj) {
        unsigned int lo = 0, hi = 0;
        int k0 = (kq << 3) + jj * 2;
        {
            int k = k0;
            if (k < 27) {
                int ic = k / 9, r9 = k - ic * 9;
                int ky = r9 / 3, kx = r9 - ky * 3;
                lo = in_s[ic][2 * w + ky][2 * col + kx];
            }
        }
        {
            int k = k0 + 1;
            if (k < 27) {
                int ic = k / 9, r9 = k - ic * 9;
                int ky = r9 / 3, kx = r9 - ky * 3;
                hi = in_s[ic][2 * w + ky][2 * col + kx];
            }
        }
        bw[jj] = lo | (hi << 16);
    }
    short8_t bv;
    {
        unsigned int* bvp = (unsigned int*)&bv;
        bvp[0] = bw[0]; bvp[1] = bw[1]; bvp[2] = bw[2]; bvp[3] = bw[3];
    }

    f32x4 acc[4];
    #pragma unroll
    for (int af = 0; af < 4; ++af) {
        acc[af] = (f32x4){0.f, 0.f, 0.f, 0.f};
        acc[af] = __builtin_amdgcn_mfma_f32_16x16x32_bf16(a[af], bv, acc[af], 0, 0, 0);
    }

    int oy = oyT * 4 + w;
    int ox = oxT * 16 + col;
    size_t pxb = ((size_t)((b * 112 + oy) * 112 + ox)) << 6;
    #pragma unroll
    for (int af = 0; af < 4; ++af) {
        unsigned int p0 = f2bf(fmaxf(acc[af][0], 0.f)) | ((unsigned int)f2bf(fmaxf(acc[af][1], 0.f)) << 16);
        unsigned int p1 = f2bf(fmaxf(acc[af][2], 0.f)) | ((unsigned int)f2bf(fmaxf(acc[af][3], 0.f)) << 16);
        uint2 pk; pk.x = p0; pk.y = p1;
        *(uint2*)&outcl[pxb + (af << 4) + (kq << 2)] = pk;
    }
}

// ---------------- eval conv2 via MFMA, 64 oc/wave (1 ds_read : 4 MFMA), fused relu+mean
// block 256 thr = 4 waves: (w&1) = oc-half (64 oc), (w>>1) = oy-half (4 rows)
// tile 8 oy x 16 ox -> LDS 17x34x64 bf16 = 72.25 KB -> 2 blocks/CU = 16 waves/CU
__global__ __launch_bounds__(256) void conv2_mfma(const unsigned short* __restrict__ g1cl,
                                                  const unsigned short* __restrict__ wpk,
                                                  float* __restrict__ gsum) {
    int oyT = blockIdx.x;            // 0..6  -> oy0 = oyT*8
    int oxT = blockIdx.y;            // 0..3  -> ox0 = oxT*16
    int b = blockIdx.z;
    int t = threadIdx.x;
    int w = t >> 6;
    int ocH = (w & 1) << 2;          // a-frag base (0 or 4) -> oc base (w&1)*64
    int oyOff = (w >> 1) << 2;       // 0 or 4 (output rows within tile)
    int lane = t & 63;
    int col = lane & 15;
    int kq = lane >> 4;

    __shared__ unsigned short tile[17 * 34 * 64];

    int iy0 = oyT * 16, ix0 = oxT * 32;
    for (int u = t; u < 17 * 34 * 8; u += 256) {
        int cg = u & 7;
        int r = u >> 3;
        int rx = r % 34, ry = r / 34;
        int iy = iy0 + ry, ix = ix0 + rx;
        uint4 v = {0, 0, 0, 0};
        if (iy < 112 && ix < 112)
            v = *(const uint4*)&g1cl[(((size_t)((b * 112 + iy) * 112 + ix)) << 6) + (cg << 3)];
        int byte = ((r << 6) + (cg << 3)) << 1;
        byte ^= ((r >> 1) & 7) << 4;
        *(uint4*)((char*)tile + byte) = v;
    }
    __syncthreads();

    f32x4 acc[4][4];
    #pragma unroll
    for (int a = 0; a < 4; ++a)
        #pragma unroll
        for (int n = 0; n < 4; ++n)
            acc[a][n] = (f32x4){0.f, 0.f, 0.f, 0.f};

    #pragma unroll 1
    for (int tap = 0; tap < 9; ++tap) {
        const int ky = tap / 3;
        const int kx = tap - ky * 3;
        const int rxl = 2 * col + kx;
        #pragma unroll
        for (int h = 0; h < 2; ++h) {
            const unsigned short* wp = wpk + ((size_t)(((tap * 2 + h) * 8) + ocH) * 64 + lane) * 8;
            short8_t a0 = *(const short8_t*)wp;
            short8_t a1 = *(const short8_t*)(wp + 512);
            short8_t a2 = *(const short8_t*)(wp + 1024);
            short8_t a3 = *(const short8_t*)(wp + 1536);
            const int e = (h << 5) + (kq << 3);
            #pragma unroll
            for (int nf = 0; nf < 4; ++nf) {
                int r = (2 * (oyOff + nf) + ky) * 34 + rxl;
                int byte = (((r << 6) + e) << 1) ^ (((r >> 1) & 7) << 4);
                short8_t bv = *(const short8_t*)((const char*)tile + byte);
                acc[0][nf] = __builtin_amdgcn_mfma_f32_16x16x32_bf16(a0, bv, acc[0][nf], 0, 0, 0);
                acc[1][nf] = __builtin_amdgcn_mfma_f32_16x16x32_bf16(a1, bv, acc[1][nf], 0, 0, 0);
                acc[2][nf] = __builtin_amdgcn_mfma_f32_16x16x32_bf16(a2, bv, acc[2][nf], 0, 0, 0);
                acc[3][nf] = __builtin_amdgcn_mfma_f32_16x16x32_bf16(a3, bv, acc[3][nf], 0, 0, 0);
            }
        }
    }

    #pragma unroll
    for (int a = 0; a < 4; ++a) {
        float s0 = 0.f, s1 = 0.f, s2 = 0.f, s3 = 0.f;
        #pragma unroll
        for (int nf = 0; nf < 4; ++nf) {
            s0 += fmaxf(acc[a][nf][0], 0.f);
            s1 += fmaxf(acc[a][nf][1], 0.f);
            s2 += fmaxf(acc[a][nf][2], 0.f);
            s3 += fmaxf(acc[a][nf][3], 0.f);
        }
        #pragma unroll
        for (int off = 1; off < 16; off <<= 1) {
            s0 += __shfl_xor(s0, off);
            s1 += __shfl_xor(s1, off);
            s2 += __shfl_xor(s2, off);
            s3 += __shfl_xor(s3, off);
        }
        if (col == 0) {
            int ocb = (w & 1) * 64 + a * 16 + kq * 4;
            atomicAdd(&gsum[b * 128 + ocb + 0], s0);
            atomicAdd(&gsum[b * 128 + ocb + 1], s1);
            atomicAdd(&gsum[b * 128 + ocb + 2], s2);
            atomicAdd(&gsum[b * 128 + ocb + 3], s3);
        }
    }
}

// ---------------- final FC: mean = gsum/3136 ; [B,128] @ [128,10] + b
__global__ void fc_kernel(const float* __restrict__ gsum, const float* __restrict__ fcw,
                          const float* __restrict__ fcb, float* __restrict__ out) {
    int gid = blockIdx.x * blockDim.x + threadIdx.x;
    if (gid >= BB * NCLS) return;
    int cls = gid % NCLS, b = gid / NCLS;
    float s = 0.f;
    for (int c = 0; c < 128; ++c) s += gsum[b * 128 + c] * fcw[c * NCLS + cls];
    out[gid] = fcb[cls] + s * (1.f / 3136.f);
}

extern "C" void kernel_launch(void* const* d_in, const int* in_sizes, int n_in,
                              void* d_out, int out_size, void* d_ws, size_t ws_size,
                              hipStream_t stream) {
    const float* ff64  = (const float*)d_in[0];
    const float* ff224 = (const float*)d_in[1];
    const float* sw1   = (const float*)d_in[2];
    const float* sw2   = (const float*)d_in[3];
    const float* polw  = (const float*)d_in[4];
    const float* polb  = (const float*)d_in[5];
    const float* ew1   = (const float*)d_in[6];
    const float* ew2   = (const float*)d_in[7];
    const float* fcw   = (const float*)d_in[8];
    const float* fcb   = (const float*)d_in[9];
    float* out = (float*)d_out;

    float* ws = (float*)d_ws;
    float* skim_res = ws;                       // 196608 f
    float* h1 = skim_res + 196608;              // 524288 f
    float* gsum2 = h1 + 524288;                 // 1024 f
    float* gsum = gsum2 + 1024;                 // 2048 f
    unsigned short* g1cl = (unsigned short*)(gsum + 2048);  // 12845056 bf16
    unsigned short* wpk  = g1cl + 12845056;     // 73728 bf16
    unsigned short* wpk1 = wpk + 73728;         // 2048 bf16

    // 1. skim resize (float4) + weight pack + zero accumulators
    prep_all<<<480, 256, 0, stream>>>(ff64, ew2, ew1, skim_res, wpk, wpk1, gsum, gsum2);

    // 2-3. skim convs (exact fp32)
    sconv1_t<<<512, 256, 0, stream>>>(skim_res, sw1, h1);
    sconv2_t<<<dim3(16, 2, BB), 256, 0, stream>>>(h1, sw2, gsum2);

    // 4. eval conv1 FUSED: policy/top-5 + gather-resize + MFMA
    conv1_fused<<<dim3(7, 28, BB), 256, 0, stream>>>(ff224, gsum2, polw, polb, wpk1, g1cl);

    // 5. eval conv2 (MFMA, 64 oc/wave) + fused relu/mean
    conv2_mfma<<<dim3(7, 4, BB), 256, 0, stream>>>(g1cl, wpk, gsum);

    // 6. final FC
    fc_kernel<<<1, 256, 0, stream>>>(gsum, fcw, fcb, out);
}

// Round 17
// 105.426 us; speedup vs baseline: 1.0111x; 1.0111x over previous
//
#include <hip/hip_runtime.h>

#define BB 16
#define TT 30
#define NSEL 5
#define NCLS 10

typedef __attribute__((ext_vector_type(8))) short short8_t;
typedef __attribute__((ext_vector_type(4))) float f32x4;

__device__ inline unsigned short f2bf(float x) {
    unsigned int u = __float_as_uint(x);
    unsigned int r = u + 0x7FFFu + ((u >> 16) & 1u);
    return (unsigned short)(r >> 16);
}

// ---------------- prep_all: blocks 0..191 skim resize (float4); 192..479 weight pack + zeroing
__global__ __launch_bounds__(256) void prep_all(const float* __restrict__ ff64,
                                                const float* __restrict__ w2,
                                                const float* __restrict__ w1,
                                                float* __restrict__ skim_res,
                                                unsigned short* __restrict__ wpk,
                                                unsigned short* __restrict__ wpk1,
                                                float* __restrict__ gsum,
                                                float* __restrict__ gsum2) {
    int bid = blockIdx.x;
    int t = threadIdx.x;
    if (bid < 192) {
        int gid = bid * 256 + t;
        int xg = gid & 15;
        int oy = (gid >> 4) & 63;
        int bc = gid >> 10;
        int c = bc % 3, b = bc / 3;
        int ox0 = xg * 4;
        float sample = 30.f * (float)oy + 14.5f;
        int jlo = max(0, 30 * oy - 16);
        int jhi = min(TT * 64 - 1, 30 * oy + 45);
        float ax = 0.f, ay = 0.f, az = 0.f, aw = 0.f, ws = 0.f;
        for (int j = jlo; j <= jhi; ++j) {
            float w = fmaxf(0.f, 1.f - fabsf(sample - (float)j) * (1.f / 30.f));
            int tt = j >> 6, y = j & 63;
            const float4 v = *(const float4*)&ff64[(((b * TT + tt) * 3 + c) << 12) + (y << 6) + ox0];
            ax += w * v.x; ay += w * v.y; az += w * v.z; aw += w * v.w;
            ws += w;
        }
        float inv = 1.f / ws;
        float4 r; r.x = ax * inv; r.y = ay * inv; r.z = az * inv; r.w = aw * inv;
        *(float4*)&skim_res[(((b * 3 + c) << 6) + oy) * 64 + ox0] = r;
    } else {
        int i = (bid - 192) * 256 + t;
        if (i < BB * 128) gsum[i] = 0.f;
        if (i < BB * 64) gsum2[i] = 0.f;
        if (i < 4 * 64 * 8) {
            int j = i & 7;
            int lane = (i >> 3) & 63;
            int af = i >> 9;
            int oc = af * 16 + (lane & 15);
            int k = ((lane >> 4) << 3) + j;
            wpk1[i] = (k < 27) ? f2bf(w1[oc * 27 + k]) : (unsigned short)0;
        }
        if (i < 9 * 2 * 8 * 64 * 8) {
            int j = i & 7;
            int lane = (i >> 3) & 63;
            int af = (i >> 9) & 7;
            int h = (i >> 12) & 1;
            int tap = i >> 13;
            int oc = af * 16 + (lane & 15);
            int ic = h * 32 + ((lane >> 4) << 3) + j;
            int ky = tap / 3, kx = tap % 3;
            wpk[i] = f2bf(w2[((size_t)(oc * 64 + ic)) * 9 + ky * 3 + kx]);
        }
    }
}

// ---------------- skim conv1+conv2 FUSED (exact fp32): skim_res -> gsum2[16,64]
// grid (16 oy, 2 ocg, 16 b). Each block computes its 3 needed h1 rows (all 32 ch)
// in-block from skim_res (identical ch->ky->kx order & guards => bit-identical h1),
// then runs the conv2 phase unchanged. Eliminates the h1 round-trip + one kernel.
__global__ __launch_bounds__(256) void sconv_fused(const float* __restrict__ skim_res,
                                                   const float* __restrict__ w1,
                                                   const float* __restrict__ w2,
                                                   float* __restrict__ gsum2) {
    int oy = blockIdx.x;
    int ocg = blockIdx.y;
    int b = blockIdx.z;
    int t = threadIdx.x;
    int oc = t & 31;
    int oxg = t >> 5;

    __shared__ float sr_s[3][7][64];   // skim_res rows 4oy .. 4oy+6
    __shared__ float w1_s[27][32];
    __shared__ float in_s[32][3][32];  // h1 rows 2oy..2oy+2, computed in-block
    __shared__ float w_s[288 * 32];    // [R][oc ^ (R&31)]

    int ry0 = oy * 4;
    for (int u = t; u < 3 * 7 * 64; u += 256) {
        int ix = u & 63;
        int ry = (u >> 6) % 7;
        int ch = u / 448;
        int row = ry0 + ry;
        sr_s[ch][ry][ix] = (row < 64) ? skim_res[(((b * 3 + ch) << 6) + row) * 64 + ix] : 0.f;
    }
    for (int u = t; u < 864; u += 256) {
        int o = u & 31;
        int k = u >> 5;
        w1_s[k][o] = w1[o * 27 + k];
    }
    for (int u = t; u < 9216; u += 256) {
        int ocl = u / 288;
        int rem = u - ocl * 288;
        w_s[rem * 32 + (ocl ^ (rem & 31))] = w2[(ocg * 32 + ocl) * 288 + rem];
    }
    __syncthreads();

    // conv1 phase: in_s[o1][ry][ix] = relu(conv1(skim_res)) at h1 row 2oy+ry
    for (int u = t; u < 32 * 3 * 32; u += 256) {
        int ix = u & 31;
        int ry = (u >> 5) % 3;
        int o1 = u / 96;
        int iy1 = 2 * oy + ry;
        float v = 0.f;
        if (iy1 < 32) {
            float acc = 0.f;
            #pragma unroll
            for (int ch = 0; ch < 3; ++ch) {
                #pragma unroll
                for (int ky = 0; ky < 3; ++ky) {
                    int lr = 2 * ry + ky;          // local row in sr_s
                    #pragma unroll
                    for (int kx = 0; kx < 3; ++kx) {
                        int col = 2 * ix + kx;
                        float x = (col < 64) ? sr_s[ch][lr][col] : 0.f;
                        acc += w1_s[ch * 9 + ky * 3 + kx][o1] * x;
                    }
                }
            }
            v = fmaxf(acc, 0.f);
        }
        in_s[o1][ry][ix] = v;
    }
    __syncthreads();

    // conv2 phase (unchanged from sconv2_t)
    float acc0 = 0.f, acc1 = 0.f;
    for (int ic = 0; ic < 32; ++ic) {
        #pragma unroll
        for (int ky = 0; ky < 3; ++ky) {
            float xv[5];
            #pragma unroll
            for (int i = 0; i < 5; ++i) {
                int ix = oxg * 4 + i;
                xv[i] = (ix < 32) ? in_s[ic][ky][ix] : 0.f;
            }
            #pragma unroll
            for (int kx = 0; kx < 3; ++kx) {
                int R = ic * 9 + ky * 3 + kx;
                float wv = w_s[R * 32 + (oc ^ (R & 31))];
                acc0 += wv * xv[kx];
                acc1 += wv * xv[2 + kx];
            }
        }
    }
    float ps = fmaxf(acc0, 0.f) + fmaxf(acc1, 0.f);
    ps += __shfl_xor(ps, 32);
    if ((t & 32) == 0) atomicAdd(&gsum2[b * 64 + ocg * 32 + oc], ps);
}

// ---------------- eval conv1 FUSED: policy/top-5 + gather-resize staging + MFMA
__global__ __launch_bounds__(256) void conv1_fused(const float* __restrict__ ff224,
                                                   const float* __restrict__ gsum2,
                                                   const float* __restrict__ pol_w,
                                                   const float* __restrict__ pol_b,
                                                   const unsigned short* __restrict__ wpk1,
                                                   unsigned short* __restrict__ outcl) {
    int oxT = blockIdx.x;            // 0..6
    int oyT = blockIdx.y;            // 0..27
    int b = blockIdx.z;
    int t = threadIdx.x;
    int w = t >> 6;                  // wave -> oy = oyT*4 + w
    int lane = t & 63;
    int col = lane & 15;
    int kq = lane >> 4;

    __shared__ float fea[64];
    __shared__ float logits[TT];
    __shared__ unsigned char insel[TT];
    __shared__ int sidx[NSEL];
    __shared__ unsigned short in_s[3][9][36];

    if (t < 64) fea[t] = fmaxf(gsum2[b * 64 + t] * (1.f / 256.f), 0.f);
    __syncthreads();
    if (t < TT) {
        float l = pol_b[t];
        for (int cc = 0; cc < 64; ++cc) l += fea[cc] * pol_w[cc * TT + t];
        logits[t] = l;
    }
    __syncthreads();
    if (t < TT) {
        float li = logits[t];
        int rank = 0;
        for (int j = 0; j < TT; ++j) {
            float lj = logits[j];
            rank += (lj > li) || (lj == li && j < t);
        }
        insel[t] = (rank < NSEL) ? 1 : 0;
    }
    __syncthreads();
    if (t < TT && insel[t]) {
        int pos = 0;
        for (int j = 0; j < t; ++j) pos += insel[j];
        sidx[pos] = t;
    }
    __syncthreads();

    int iy0 = oyT * 8, ix0 = oxT * 32;
    if (t < 243) {
        int rx0 = (t % 9) * 4;
        int ry = (t / 9) % 9;
        int ic = t / 81;
        int oy = iy0 + ry;
        int ox0 = ix0 + rx0;
        ushort4 v4 = {0, 0, 0, 0};
        if (oy < 224 && ox0 < 224) {
            float sample = 5.f * (float)oy + 2.f;
            int j0 = 5 * oy - 3;
            float ax = 0.f, ay = 0.f, az = 0.f, aw = 0.f, wsum = 0.f;
            #pragma unroll
            for (int dj = 0; dj < 11; ++dj) {
                int j = j0 + dj;
                float wt = (j >= 0 && j < NSEL * 224)
                               ? fmaxf(0.f, 1.f - fabsf(sample - (float)j) * 0.2f) : 0.f;
                int jc = min(max(j, 0), NSEL * 224 - 1);
                int s = jc / 224, y = jc % 224;
                int tf = sidx[s];
                const float4 v = *(const float4*)&ff224[((size_t)((b * TT + tf) * 3 + ic) * 224 + y) * 224 + ox0];
                ax += wt * v.x; ay += wt * v.y; az += wt * v.z; aw += wt * v.w;
                wsum += wt;
            }
            float inv = 1.f / wsum;
            v4.x = f2bf(ax * inv); v4.y = f2bf(ay * inv);
            v4.z = f2bf(az * inv); v4.w = f2bf(aw * inv);
        }
        *(ushort4*)&in_s[ic][ry][rx0] = v4;
    }
    __syncthreads();

    short8_t a[4];
    #pragma unroll
    for (int af = 0; af < 4; ++af)
        a[af] = *(const short8_t*)&wpk1[((af << 6) + lane) << 3];

    unsigned int bw[4];
    #pragma unroll
    for (int jj = 0; jj < 4; ++jj) {
        unsigned int lo = 0, hi = 0;
        int k0 = (kq << 3) + jj * 2;
        {
            int k = k0;
            if (k < 27) {
                int ic = k / 9, r9 = k - ic * 9;
                int ky = r9 / 3, kx = r9 - ky * 3;
                lo = in_s[ic][2 * w + ky][2 * col + kx];
            }
        }
        {
            int k = k0 + 1;
            if (k < 27) {
                int ic = k / 9, r9 = k - ic * 9;
                int ky = r9 / 3, kx = r9 - ky * 3;
                hi = in_s[ic][2 * w + ky][2 * col + kx];
            }
        }
        bw[jj] = lo | (hi << 16);
    }
    short8_t bv;
    {
        unsigned int* bvp = (unsigned int*)&bv;
        bvp[0] = bw[0]; bvp[1] = bw[1]; bvp[2] = bw[2]; bvp[3] = bw[3];
    }

    f32x4 acc[4];
    #pragma unroll
    for (int af = 0; af < 4; ++af) {
        acc[af] = (f32x4){0.f, 0.f, 0.f, 0.f};
        acc[af] = __builtin_amdgcn_mfma_f32_16x16x32_bf16(a[af], bv, acc[af], 0, 0, 0);
    }

    int oy = oyT * 4 + w;
    int ox = oxT * 16 + col;
    size_t pxb = ((size_t)((b * 112 + oy) * 112 + ox)) << 6;
    #pragma unroll
    for (int af = 0; af < 4; ++af) {
        unsigned int p0 = f2bf(fmaxf(acc[af][0], 0.f)) | ((unsigned int)f2bf(fmaxf(acc[af][1], 0.f)) << 16);
        unsigned int p1 = f2bf(fmaxf(acc[af][2], 0.f)) | ((unsigned int)f2bf(fmaxf(acc[af][3], 0.f)) << 16);
        uint2 pk; pk.x = p0; pk.y = p1;
        *(uint2*)&outcl[pxb + (af << 4) + (kq << 2)] = pk;
    }
}

// ---------------- eval conv2 via MFMA + LDS input, fused relu+mean -> gsum[B,128]
// (R15 version: 32 oc/wave, tile 4 oy x 16 ox, 38.25 KB LDS)
__global__ __launch_bounds__(256) void conv2_mfma(const unsigned short* __restrict__ g1cl,
                                                  const unsigned short* __restrict__ wpk,
                                                  float* __restrict__ gsum) {
    int oyT = blockIdx.x;            // 0..13 -> oy0 = oyT*4
    int oxT = blockIdx.y;            // 0..3  -> ox0 = oxT*16
    int b = blockIdx.z;
    int t = threadIdx.x;
    int wv = t >> 6;                 // 0..3 -> oc base wv*32
    int lane = t & 63;
    int col = lane & 15;
    int kq = lane >> 4;

    __shared__ unsigned short tile[9 * 34 * 64];

    int iy0 = oyT * 8, ix0 = oxT * 32;
    for (int u = t; u < 9 * 34 * 8; u += 256) {
        int cg = u & 7;
        int r = u >> 3;
        int rx = r % 34, ry = r / 34;
        int iy = iy0 + ry, ix = ix0 + rx;
        uint4 v = {0, 0, 0, 0};
        if (iy < 112 && ix < 112)
            v = *(const uint4*)&g1cl[(((size_t)((b * 112 + iy) * 112 + ix)) << 6) + (cg << 3)];
        int byte = ((r << 6) + (cg << 3)) << 1;
        byte ^= ((r >> 1) & 7) << 4;
        *(uint4*)((char*)tile + byte) = v;
    }
    __syncthreads();

    f32x4 acc[2][4];
    #pragma unroll
    for (int a = 0; a < 2; ++a)
        #pragma unroll
        for (int n = 0; n < 4; ++n)
            acc[a][n] = (f32x4){0.f, 0.f, 0.f, 0.f};

    #pragma unroll 1
    for (int tap = 0; tap < 9; ++tap) {
        const int ky = tap / 3;
        const int kx = tap - ky * 3;
        const int rxl = 2 * col + kx;
        #pragma unroll
        for (int h = 0; h < 2; ++h) {
            const unsigned short* wp = wpk + ((size_t)(((tap * 2 + h) * 8) + (wv << 1)) * 64 + lane) * 8;
            short8_t a0 = *(const short8_t*)wp;
            short8_t a1 = *(const short8_t*)(wp + 512);
            const int e = (h << 5) + (kq << 3);
            #pragma unroll
            for (int nf = 0; nf < 4; ++nf) {
                int r = (2 * nf + ky) * 34 + rxl;
                int byte = (((r << 6) + e) << 1) ^ (((r >> 1) & 7) << 4);
                short8_t bv = *(const short8_t*)((const char*)tile + byte);
                acc[0][nf] = __builtin_amdgcn_mfma_f32_16x16x32_bf16(a0, bv, acc[0][nf], 0, 0, 0);
                acc[1][nf] = __builtin_amdgcn_mfma_f32_16x16x32_bf16(a1, bv, acc[1][nf], 0, 0, 0);
            }
        }
    }

    #pragma unroll
    for (int a = 0; a < 2; ++a) {
        float s0 = 0.f, s1 = 0.f, s2 = 0.f, s3 = 0.f;
        #pragma unroll
        for (int nf = 0; nf < 4; ++nf) {
            s0 += fmaxf(acc[a][nf][0], 0.f);
            s1 += fmaxf(acc[a][nf][1], 0.f);
            s2 += fmaxf(acc[a][nf][2], 0.f);
            s3 += fmaxf(acc[a][nf][3], 0.f);
        }
        #pragma unroll
        for (int off = 1; off < 16; off <<= 1) {
            s0 += __shfl_xor(s0, off);
            s1 += __shfl_xor(s1, off);
            s2 += __shfl_xor(s2, off);
            s3 += __shfl_xor(s3, off);
        }
        if (col == 0) {
            int ocb = wv * 32 + a * 16 + kq * 4;
            atomicAdd(&gsum[b * 128 + ocb + 0], s0);
            atomicAdd(&gsum[b * 128 + ocb + 1], s1);
            atomicAdd(&gsum[b * 128 + ocb + 2], s2);
            atomicAdd(&gsum[b * 128 + ocb + 3], s3);
        }
    }
}

// ---------------- final FC: mean = gsum/3136 ; [B,128] @ [128,10] + b
__global__ void fc_kernel(const float* __restrict__ gsum, const float* __restrict__ fcw,
                          const float* __restrict__ fcb, float* __restrict__ out) {
    int gid = blockIdx.x * blockDim.x + threadIdx.x;
    if (gid >= BB * NCLS) return;
    int cls = gid % NCLS, b = gid / NCLS;
    float s = 0.f;
    for (int c = 0; c < 128; ++c) s += gsum[b * 128 + c] * fcw[c * NCLS + cls];
    out[gid] = fcb[cls] + s * (1.f / 3136.f);
}

extern "C" void kernel_launch(void* const* d_in, const int* in_sizes, int n_in,
                              void* d_out, int out_size, void* d_ws, size_t ws_size,
                              hipStream_t stream) {
    const float* ff64  = (const float*)d_in[0];
    const float* ff224 = (const float*)d_in[1];
    const float* sw1   = (const float*)d_in[2];
    const float* sw2   = (const float*)d_in[3];
    const float* polw  = (const float*)d_in[4];
    const float* polb  = (const float*)d_in[5];
    const float* ew1   = (const float*)d_in[6];
    const float* ew2   = (const float*)d_in[7];
    const float* fcw   = (const float*)d_in[8];
    const float* fcb   = (const float*)d_in[9];
    float* out = (float*)d_out;

    float* ws = (float*)d_ws;
    float* skim_res = ws;                       // 196608 f
    float* gsum2 = skim_res + 196608;           // 1024 f
    float* gsum = gsum2 + 1024;                 // 2048 f
    unsigned short* g1cl = (unsigned short*)(gsum + 2048);  // 12845056 bf16
    unsigned short* wpk  = g1cl + 12845056;     // 73728 bf16
    unsigned short* wpk1 = wpk + 73728;         // 2048 bf16

    // 1. skim resize (float4) + weight pack + zero accumulators
    prep_all<<<480, 256, 0, stream>>>(ff64, ew2, ew1, skim_res, wpk, wpk1, gsum, gsum2);

    // 2. skim conv1+conv2 fused (exact fp32) -> gsum2
    sconv_fused<<<dim3(16, 2, BB), 256, 0, stream>>>(skim_res, sw1, sw2, gsum2);

    // 3. eval conv1 FUSED: policy/top-5 + gather-resize + MFMA
    conv1_fused<<<dim3(7, 28, BB), 256, 0, stream>>>(ff224, gsum2, polw, polb, wpk1, g1cl);

    // 4. eval conv2 (MFMA) + fused relu/mean
    conv2_mfma<<<dim3(14, 4, BB), 256, 0, stream>>>(g1cl, wpk, gsum);

    // 5. final FC
    fc_kernel<<<1, 256, 0, stream>>>(gsum, fcw, fcb, out);
}

// Round 18
// 103.030 us; speedup vs baseline: 1.0346x; 1.0233x over previous
//
#include <hip/hip_runtime.h>

#define BB 16
#define TT 30
#define NSEL 5
#define NCLS 10

typedef __attribute__((ext_vector_type(8))) short short8_t;
typedef __attribute__((ext_vector_type(4))) float f32x4;

__device__ inline unsigned short f2bf(float x) {
    unsigned int u = __float_as_uint(x);
    unsigned int r = u + 0x7FFFu + ((u >> 16) & 1u);
    return (unsigned short)(r >> 16);
}

// ---------------- prep_all: blocks 0..191 skim resize (float4); 192..479 weight pack + zeroing
__global__ __launch_bounds__(256) void prep_all(const float* __restrict__ ff64,
                                                const float* __restrict__ w2,
                                                const float* __restrict__ w1,
                                                float* __restrict__ skim_res,
                                                unsigned short* __restrict__ wpk,
                                                unsigned short* __restrict__ wpk1,
                                                float* __restrict__ gsum,
                                                float* __restrict__ gsum2) {
    int bid = blockIdx.x;
    int t = threadIdx.x;
    if (bid < 192) {
        int gid = bid * 256 + t;
        int xg = gid & 15;
        int oy = (gid >> 4) & 63;
        int bc = gid >> 10;
        int c = bc % 3, b = bc / 3;
        int ox0 = xg * 4;
        float sample = 30.f * (float)oy + 14.5f;
        int jlo = max(0, 30 * oy - 16);
        int jhi = min(TT * 64 - 1, 30 * oy + 45);
        float ax = 0.f, ay = 0.f, az = 0.f, aw = 0.f, ws = 0.f;
        for (int j = jlo; j <= jhi; ++j) {
            float w = fmaxf(0.f, 1.f - fabsf(sample - (float)j) * (1.f / 30.f));
            int tt = j >> 6, y = j & 63;
            const float4 v = *(const float4*)&ff64[(((b * TT + tt) * 3 + c) << 12) + (y << 6) + ox0];
            ax += w * v.x; ay += w * v.y; az += w * v.z; aw += w * v.w;
            ws += w;
        }
        float inv = 1.f / ws;
        float4 r; r.x = ax * inv; r.y = ay * inv; r.z = az * inv; r.w = aw * inv;
        *(float4*)&skim_res[(((b * 3 + c) << 6) + oy) * 64 + ox0] = r;
    } else {
        int i = (bid - 192) * 256 + t;
        if (i < BB * 128) gsum[i] = 0.f;
        if (i < BB * 64) gsum2[i] = 0.f;
        if (i < 4 * 64 * 8) {
            int j = i & 7;
            int lane = (i >> 3) & 63;
            int af = i >> 9;
            int oc = af * 16 + (lane & 15);
            int k = ((lane >> 4) << 3) + j;
            wpk1[i] = (k < 27) ? f2bf(w1[oc * 27 + k]) : (unsigned short)0;
        }
        if (i < 9 * 2 * 8 * 64 * 8) {
            int j = i & 7;
            int lane = (i >> 3) & 63;
            int af = (i >> 9) & 7;
            int h = (i >> 12) & 1;
            int tap = i >> 13;
            int oc = af * 16 + (lane & 15);
            int ic = h * 32 + ((lane >> 4) << 3) + j;
            int ky = tap / 3, kx = tap % 3;
            wpk[i] = f2bf(w2[((size_t)(oc * 64 + ic)) * 9 + ky * 3 + kx]);
        }
    }
}

// ---------------- skim conv1+conv2 FUSED (exact fp32): skim_res -> gsum2[16,64]
__global__ __launch_bounds__(256) void sconv_fused(const float* __restrict__ skim_res,
                                                   const float* __restrict__ w1,
                                                   const float* __restrict__ w2,
                                                   float* __restrict__ gsum2) {
    int oy = blockIdx.x;
    int ocg = blockIdx.y;
    int b = blockIdx.z;
    int t = threadIdx.x;
    int oc = t & 31;
    int oxg = t >> 5;

    __shared__ float sr_s[3][7][64];   // skim_res rows 4oy .. 4oy+6
    __shared__ float w1_s[27][32];
    __shared__ float in_s[32][3][32];  // h1 rows 2oy..2oy+2, computed in-block
    __shared__ float w_s[288 * 32];    // [R][oc ^ (R&31)]

    int ry0 = oy * 4;
    for (int u = t; u < 3 * 7 * 64; u += 256) {
        int ix = u & 63;
        int ry = (u >> 6) % 7;
        int ch = u / 448;
        int row = ry0 + ry;
        sr_s[ch][ry][ix] = (row < 64) ? skim_res[(((b * 3 + ch) << 6) + row) * 64 + ix] : 0.f;
    }
    for (int u = t; u < 864; u += 256) {
        int o = u & 31;
        int k = u >> 5;
        w1_s[k][o] = w1[o * 27 + k];
    }
    for (int u = t; u < 9216; u += 256) {
        int ocl = u / 288;
        int rem = u - ocl * 288;
        w_s[rem * 32 + (ocl ^ (rem & 31))] = w2[(ocg * 32 + ocl) * 288 + rem];
    }
    __syncthreads();

    for (int u = t; u < 32 * 3 * 32; u += 256) {
        int ix = u & 31;
        int ry = (u >> 5) % 3;
        int o1 = u / 96;
        int iy1 = 2 * oy + ry;
        float v = 0.f;
        if (iy1 < 32) {
            float acc = 0.f;
            #pragma unroll
            for (int ch = 0; ch < 3; ++ch) {
                #pragma unroll
                for (int ky = 0; ky < 3; ++ky) {
                    int lr = 2 * ry + ky;
                    #pragma unroll
                    for (int kx = 0; kx < 3; ++kx) {
                        int col = 2 * ix + kx;
                        float x = (col < 64) ? sr_s[ch][lr][col] : 0.f;
                        acc += w1_s[ch * 9 + ky * 3 + kx][o1] * x;
                    }
                }
            }
            v = fmaxf(acc, 0.f);
        }
        in_s[o1][ry][ix] = v;
    }
    __syncthreads();

    float acc0 = 0.f, acc1 = 0.f;
    for (int ic = 0; ic < 32; ++ic) {
        #pragma unroll
        for (int ky = 0; ky < 3; ++ky) {
            float xv[5];
            #pragma unroll
            for (int i = 0; i < 5; ++i) {
                int ix = oxg * 4 + i;
                xv[i] = (ix < 32) ? in_s[ic][ky][ix] : 0.f;
            }
            #pragma unroll
            for (int kx = 0; kx < 3; ++kx) {
                int R = ic * 9 + ky * 3 + kx;
                float wv = w_s[R * 32 + (oc ^ (R & 31))];
                acc0 += wv * xv[kx];
                acc1 += wv * xv[2 + kx];
            }
        }
    }
    float ps = fmaxf(acc0, 0.f) + fmaxf(acc1, 0.f);
    ps += __shfl_xor(ps, 32);
    if ((t & 32) == 0) atomicAdd(&gsum2[b * 64 + ocg * 32 + oc], ps);
}

// ---------------- eval conv1 FUSED: policy/top-5 + gather-resize staging + MFMA
__global__ __launch_bounds__(256) void conv1_fused(const float* __restrict__ ff224,
                                                   const float* __restrict__ gsum2,
                                                   const float* __restrict__ pol_w,
                                                   const float* __restrict__ pol_b,
                                                   const unsigned short* __restrict__ wpk1,
                                                   unsigned short* __restrict__ outcl) {
    int oxT = blockIdx.x;            // 0..6
    int oyT = blockIdx.y;            // 0..27
    int b = blockIdx.z;
    int t = threadIdx.x;
    int w = t >> 6;                  // wave -> oy = oyT*4 + w
    int lane = t & 63;
    int col = lane & 15;
    int kq = lane >> 4;

    __shared__ float fea[64];
    __shared__ float logits[TT];
    __shared__ unsigned char insel[TT];
    __shared__ int sidx[NSEL];
    __shared__ unsigned short in_s[3][9][36];

    if (t < 64) fea[t] = fmaxf(gsum2[b * 64 + t] * (1.f / 256.f), 0.f);
    __syncthreads();
    if (t < TT) {
        float l = pol_b[t];
        for (int cc = 0; cc < 64; ++cc) l += fea[cc] * pol_w[cc * TT + t];
        logits[t] = l;
    }
    __syncthreads();
    if (t < TT) {
        float li = logits[t];
        int rank = 0;
        for (int j = 0; j < TT; ++j) {
            float lj = logits[j];
            rank += (lj > li) || (lj == li && j < t);
        }
        insel[t] = (rank < NSEL) ? 1 : 0;
    }
    __syncthreads();
    if (t < TT && insel[t]) {
        int pos = 0;
        for (int j = 0; j < t; ++j) pos += insel[j];
        sidx[pos] = t;
    }
    __syncthreads();

    int iy0 = oyT * 8, ix0 = oxT * 32;
    if (t < 243) {
        int rx0 = (t % 9) * 4;
        int ry = (t / 9) % 9;
        int ic = t / 81;
        int oy = iy0 + ry;
        int ox0 = ix0 + rx0;
        ushort4 v4 = {0, 0, 0, 0};
        if (oy < 224 && ox0 < 224) {
            float sample = 5.f * (float)oy + 2.f;
            int j0 = 5 * oy - 3;
            float ax = 0.f, ay = 0.f, az = 0.f, aw = 0.f, wsum = 0.f;
            #pragma unroll
            for (int dj = 0; dj < 11; ++dj) {
                int j = j0 + dj;
                float wt = (j >= 0 && j < NSEL * 224)
                               ? fmaxf(0.f, 1.f - fabsf(sample - (float)j) * 0.2f) : 0.f;
                int jc = min(max(j, 0), NSEL * 224 - 1);
                int s = jc / 224, y = jc % 224;
                int tf = sidx[s];
                const float4 v = *(const float4*)&ff224[((size_t)((b * TT + tf) * 3 + ic) * 224 + y) * 224 + ox0];
                ax += wt * v.x; ay += wt * v.y; az += wt * v.z; aw += wt * v.w;
                wsum += wt;
            }
            float inv = 1.f / wsum;
            v4.x = f2bf(ax * inv); v4.y = f2bf(ay * inv);
            v4.z = f2bf(az * inv); v4.w = f2bf(aw * inv);
        }
        *(ushort4*)&in_s[ic][ry][rx0] = v4;
    }
    __syncthreads();

    short8_t a[4];
    #pragma unroll
    for (int af = 0; af < 4; ++af)
        a[af] = *(const short8_t*)&wpk1[((af << 6) + lane) << 3];

    unsigned int bw[4];
    #pragma unroll
    for (int jj = 0; jj < 4; ++jj) {
        unsigned int lo = 0, hi = 0;
        int k0 = (kq << 3) + jj * 2;
        {
            int k = k0;
            if (k < 27) {
                int ic = k / 9, r9 = k - ic * 9;
                int ky = r9 / 3, kx = r9 - ky * 3;
                lo = in_s[ic][2 * w + ky][2 * col + kx];
            }
        }
        {
            int k = k0 + 1;
            if (k < 27) {
                int ic = k / 9, r9 = k - ic * 9;
                int ky = r9 / 3, kx = r9 - ky * 3;
                hi = in_s[ic][2 * w + ky][2 * col + kx];
            }
        }
        bw[jj] = lo | (hi << 16);
    }
    short8_t bv;
    {
        unsigned int* bvp = (unsigned int*)&bv;
        bvp[0] = bw[0]; bvp[1] = bw[1]; bvp[2] = bw[2]; bvp[3] = bw[3];
    }

    f32x4 acc[4];
    #pragma unroll
    for (int af = 0; af < 4; ++af) {
        acc[af] = (f32x4){0.f, 0.f, 0.f, 0.f};
        acc[af] = __builtin_amdgcn_mfma_f32_16x16x32_bf16(a[af], bv, acc[af], 0, 0, 0);
    }

    int oy = oyT * 4 + w;
    int ox = oxT * 16 + col;
    size_t pxb = ((size_t)((b * 112 + oy) * 112 + ox)) << 6;
    #pragma unroll
    for (int af = 0; af < 4; ++af) {
        unsigned int p0 = f2bf(fmaxf(acc[af][0], 0.f)) | ((unsigned int)f2bf(fmaxf(acc[af][1], 0.f)) << 16);
        unsigned int p1 = f2bf(fmaxf(acc[af][2], 0.f)) | ((unsigned int)f2bf(fmaxf(acc[af][3], 0.f)) << 16);
        uint2 pk; pk.x = p0; pk.y = p1;
        *(uint2*)&outcl[pxb + (af << 4) + (kq << 2)] = pk;
    }
}

// ---------------- eval conv2 via MFMA + LDS input, fused relu+mean -> gsum[B,128]
// Staging via global_load_lds for interior tiles: LDS dest LINEAR, source address
// carries the inverse XOR-swizzle (dest = r*128 + (cg^s)*16, s=(r>>1)&7, is an
// involution on the cg bits) -> identical tile bytes to the reg-staged path.
__global__ __launch_bounds__(256) void conv2_mfma(const unsigned short* __restrict__ g1cl,
                                                  const unsigned short* __restrict__ wpk,
                                                  float* __restrict__ gsum) {
    int oyT = blockIdx.x;            // 0..13 -> oy0 = oyT*4
    int oxT = blockIdx.y;            // 0..3  -> ox0 = oxT*16
    int b = blockIdx.z;
    int t = threadIdx.x;
    int wv = t >> 6;                 // 0..3 -> oc base wv*32
    int lane = t & 63;
    int col = lane & 15;
    int kq = lane >> 4;

    __shared__ unsigned short tile[9 * 34 * 64];

    int iy0 = oyT * 8, ix0 = oxT * 32;
    bool interior = (oyT < 13) && (oxT < 3);
    if (interior) {
        // 2448 16B-slots; linear LDS dest, inverse-swizzled source
        #pragma unroll 1
        for (int it = 0; it < 10; ++it) {
            int u = it * 256 + t;
            if (u < 2448) {
                int cg = u & 7;            // linear LDS cg slot
                int r = u >> 3;
                int rx = r % 34, ry = r / 34;
                int iy = iy0 + ry, ix = ix0 + rx;
                int cgS = cg ^ ((r >> 1) & 7);   // source cg (involution)
                const unsigned short* src =
                    &g1cl[(((size_t)((b * 112 + iy) * 112 + ix)) << 6) + (cgS << 3)];
                __builtin_amdgcn_global_load_lds(
                    (const __attribute__((address_space(1))) void*)src,
                    (__attribute__((address_space(3))) void*)((char*)tile + u * 16),
                    16, 0, 0);
            }
        }
    } else {
        for (int u = t; u < 9 * 34 * 8; u += 256) {
            int cg = u & 7;
            int r = u >> 3;
            int rx = r % 34, ry = r / 34;
            int iy = iy0 + ry, ix = ix0 + rx;
            uint4 v = {0, 0, 0, 0};
            if (iy < 112 && ix < 112)
                v = *(const uint4*)&g1cl[(((size_t)((b * 112 + iy) * 112 + ix)) << 6) + (cg << 3)];
            int byte = ((r << 6) + (cg << 3)) << 1;
            byte ^= ((r >> 1) & 7) << 4;
            *(uint4*)((char*)tile + byte) = v;
        }
    }
    __syncthreads();

    f32x4 acc[2][4];
    #pragma unroll
    for (int a = 0; a < 2; ++a)
        #pragma unroll
        for (int n = 0; n < 4; ++n)
            acc[a][n] = (f32x4){0.f, 0.f, 0.f, 0.f};

    #pragma unroll 1
    for (int tap = 0; tap < 9; ++tap) {
        const int ky = tap / 3;
        const int kx = tap - ky * 3;
        const int rxl = 2 * col + kx;
        #pragma unroll
        for (int h = 0; h < 2; ++h) {
            const unsigned short* wp = wpk + ((size_t)(((tap * 2 + h) * 8) + (wv << 1)) * 64 + lane) * 8;
            short8_t a0 = *(const short8_t*)wp;
            short8_t a1 = *(const short8_t*)(wp + 512);
            const int e = (h << 5) + (kq << 3);
            #pragma unroll
            for (int nf = 0; nf < 4; ++nf) {
                int r = (2 * nf + ky) * 34 + rxl;
                int byte = (((r << 6) + e) << 1) ^ (((r >> 1) & 7) << 4);
                short8_t bv = *(const short8_t*)((const char*)tile + byte);
                acc[0][nf] = __builtin_amdgcn_mfma_f32_16x16x32_bf16(a0, bv, acc[0][nf], 0, 0, 0);
                acc[1][nf] = __builtin_amdgcn_mfma_f32_16x16x32_bf16(a1, bv, acc[1][nf], 0, 0, 0);
            }
        }
    }

    #pragma unroll
    for (int a = 0; a < 2; ++a) {
        float s0 = 0.f, s1 = 0.f, s2 = 0.f, s3 = 0.f;
        #pragma unroll
        for (int nf = 0; nf < 4; ++nf) {
            s0 += fmaxf(acc[a][nf][0], 0.f);
            s1 += fmaxf(acc[a][nf][1], 0.f);
            s2 += fmaxf(acc[a][nf][2], 0.f);
            s3 += fmaxf(acc[a][nf][3], 0.f);
        }
        #pragma unroll
        for (int off = 1; off < 16; off <<= 1) {
            s0 += __shfl_xor(s0, off);
            s1 += __shfl_xor(s1, off);
            s2 += __shfl_xor(s2, off);
            s3 += __shfl_xor(s3, off);
        }
        if (col == 0) {
            int ocb = wv * 32 + a * 16 + kq * 4;
            atomicAdd(&gsum[b * 128 + ocb + 0], s0);
            atomicAdd(&gsum[b * 128 + ocb + 1], s1);
            atomicAdd(&gsum[b * 128 + ocb + 2], s2);
            atomicAdd(&gsum[b * 128 + ocb + 3], s3);
        }
    }
}

// ---------------- final FC: mean = gsum/3136 ; [B,128] @ [128,10] + b
__global__ void fc_kernel(const float* __restrict__ gsum, const float* __restrict__ fcw,
                          const float* __restrict__ fcb, float* __restrict__ out) {
    int gid = blockIdx.x * blockDim.x + threadIdx.x;
    if (gid >= BB * NCLS) return;
    int cls = gid % NCLS, b = gid / NCLS;
    float s = 0.f;
    for (int c = 0; c < 128; ++c) s += gsum[b * 128 + c] * fcw[c * NCLS + cls];
    out[gid] = fcb[cls] + s * (1.f / 3136.f);
}

extern "C" void kernel_launch(void* const* d_in, const int* in_sizes, int n_in,
                              void* d_out, int out_size, void* d_ws, size_t ws_size,
                              hipStream_t stream) {
    const float* ff64  = (const float*)d_in[0];
    const float* ff224 = (const float*)d_in[1];
    const float* sw1   = (const float*)d_in[2];
    const float* sw2   = (const float*)d_in[3];
    const float* polw  = (const float*)d_in[4];
    const float* polb  = (const float*)d_in[5];
    const float* ew1   = (const float*)d_in[6];
    const float* ew2   = (const float*)d_in[7];
    const float* fcw   = (const float*)d_in[8];
    const float* fcb   = (const float*)d_in[9];
    float* out = (float*)d_out;

    float* ws = (float*)d_ws;
    float* skim_res = ws;                       // 196608 f
    float* gsum2 = skim_res + 196608;           // 1024 f
    float* gsum = gsum2 + 1024;                 // 2048 f
    unsigned short* g1cl = (unsigned short*)(gsum + 2048);  // 12845056 bf16
    unsigned short* wpk  = g1cl + 12845056;     // 73728 bf16
    unsigned short* wpk1 = wpk + 73728;         // 2048 bf16

    // 1. skim resize (float4) + weight pack + zero accumulators
    prep_all<<<480, 256, 0, stream>>>(ff64, ew2, ew1, skim_res, wpk, wpk1, gsum, gsum2);

    // 2. skim conv1+conv2 fused (exact fp32) -> gsum2
    sconv_fused<<<dim3(16, 2, BB), 256, 0, stream>>>(skim_res, sw1, sw2, gsum2);

    // 3. eval conv1 FUSED: policy/top-5 + gather-resize + MFMA
    conv1_fused<<<dim3(7, 28, BB), 256, 0, stream>>>(ff224, gsum2, polw, polb, wpk1, g1cl);

    // 4. eval conv2 (MFMA, global_load_lds staging) + fused relu/mean
    conv2_mfma<<<dim3(14, 4, BB), 256, 0, stream>>>(g1cl, wpk, gsum);

    // 5. final FC
    fc_kernel<<<1, 256, 0, stream>>>(gsum, fcw, fcb, out);
}

// Round 19
// 97.022 us; speedup vs baseline: 1.0987x; 1.0619x over previous
//
#include <hip/hip_runtime.h>

#define BB 16
#define TT 30
#define NSEL 5
#define NCLS 10

typedef __attribute__((ext_vector_type(8))) short short8_t;
typedef __attribute__((ext_vector_type(4))) float f32x4;

__device__ inline unsigned short f2bf(float x) {
    unsigned int u = __float_as_uint(x);
    unsigned int r = u + 0x7FFFu + ((u >> 16) & 1u);
    return (unsigned short)(r >> 16);
}

// ---------------- prep_all: blocks 0..191 skim resize (float4); 192..479 weight pack + zeroing
__global__ __launch_bounds__(256) void prep_all(const float* __restrict__ ff64,
                                                const float* __restrict__ w2,
                                                const float* __restrict__ w1,
                                                float* __restrict__ skim_res,
                                                unsigned short* __restrict__ wpk,
                                                unsigned short* __restrict__ wpk1,
                                                float* __restrict__ gsum,
                                                float* __restrict__ gsum2) {
    int bid = blockIdx.x;
    int t = threadIdx.x;
    if (bid < 192) {
        int gid = bid * 256 + t;
        int xg = gid & 15;
        int oy = (gid >> 4) & 63;
        int bc = gid >> 10;
        int c = bc % 3, b = bc / 3;
        int ox0 = xg * 4;
        float sample = 30.f * (float)oy + 14.5f;
        int jlo = max(0, 30 * oy - 16);
        int jhi = min(TT * 64 - 1, 30 * oy + 45);
        float ax = 0.f, ay = 0.f, az = 0.f, aw = 0.f, ws = 0.f;
        for (int j = jlo; j <= jhi; ++j) {
            float w = fmaxf(0.f, 1.f - fabsf(sample - (float)j) * (1.f / 30.f));
            int tt = j >> 6, y = j & 63;
            const float4 v = *(const float4*)&ff64[(((b * TT + tt) * 3 + c) << 12) + (y << 6) + ox0];
            ax += w * v.x; ay += w * v.y; az += w * v.z; aw += w * v.w;
            ws += w;
        }
        float inv = 1.f / ws;
        float4 r; r.x = ax * inv; r.y = ay * inv; r.z = az * inv; r.w = aw * inv;
        *(float4*)&skim_res[(((b * 3 + c) << 6) + oy) * 64 + ox0] = r;
    } else {
        int i = (bid - 192) * 256 + t;
        if (i < BB * 128) gsum[i] = 0.f;
        if (i < BB * 64) gsum2[i] = 0.f;
        if (i < 4 * 64 * 8) {
            int j = i & 7;
            int lane = (i >> 3) & 63;
            int af = i >> 9;
            int oc = af * 16 + (lane & 15);
            int k = ((lane >> 4) << 3) + j;
            wpk1[i] = (k < 27) ? f2bf(w1[oc * 27 + k]) : (unsigned short)0;
        }
        if (i < 9 * 2 * 8 * 64 * 8) {
            int j = i & 7;
            int lane = (i >> 3) & 63;
            int af = (i >> 9) & 7;
            int h = (i >> 12) & 1;
            int tap = i >> 13;
            int oc = af * 16 + (lane & 15);
            int ic = h * 32 + ((lane >> 4) << 3) + j;
            int ky = tap / 3, kx = tap % 3;
            wpk[i] = f2bf(w2[((size_t)(oc * 64 + ic)) * 9 + ky * 3 + kx]);
        }
    }
}

// ---------------- skim conv1+conv2 FUSED (exact fp32): skim_res -> gsum2[16,64]
__global__ __launch_bounds__(256) void sconv_fused(const float* __restrict__ skim_res,
                                                   const float* __restrict__ w1,
                                                   const float* __restrict__ w2,
                                                   float* __restrict__ gsum2) {
    int oy = blockIdx.x;
    int ocg = blockIdx.y;
    int b = blockIdx.z;
    int t = threadIdx.x;
    int oc = t & 31;
    int oxg = t >> 5;

    __shared__ float sr_s[3][7][64];
    __shared__ float w1_s[27][32];
    __shared__ float in_s[32][3][32];
    __shared__ float w_s[288 * 32];

    int ry0 = oy * 4;
    for (int u = t; u < 3 * 7 * 64; u += 256) {
        int ix = u & 63;
        int ry = (u >> 6) % 7;
        int ch = u / 448;
        int row = ry0 + ry;
        sr_s[ch][ry][ix] = (row < 64) ? skim_res[(((b * 3 + ch) << 6) + row) * 64 + ix] : 0.f;
    }
    for (int u = t; u < 864; u += 256) {
        int o = u & 31;
        int k = u >> 5;
        w1_s[k][o] = w1[o * 27 + k];
    }
    for (int u = t; u < 9216; u += 256) {
        int ocl = u / 288;
        int rem = u - ocl * 288;
        w_s[rem * 32 + (ocl ^ (rem & 31))] = w2[(ocg * 32 + ocl) * 288 + rem];
    }
    __syncthreads();

    for (int u = t; u < 32 * 3 * 32; u += 256) {
        int ix = u & 31;
        int ry = (u >> 5) % 3;
        int o1 = u / 96;
        int iy1 = 2 * oy + ry;
        float v = 0.f;
        if (iy1 < 32) {
            float acc = 0.f;
            #pragma unroll
            for (int ch = 0; ch < 3; ++ch) {
                #pragma unroll
                for (int ky = 0; ky < 3; ++ky) {
                    int lr = 2 * ry + ky;
                    #pragma unroll
                    for (int kx = 0; kx < 3; ++kx) {
                        int col = 2 * ix + kx;
                        float x = (col < 64) ? sr_s[ch][lr][col] : 0.f;
                        acc += w1_s[ch * 9 + ky * 3 + kx][o1] * x;
                    }
                }
            }
            v = fmaxf(acc, 0.f);
        }
        in_s[o1][ry][ix] = v;
    }
    __syncthreads();

    float acc0 = 0.f, acc1 = 0.f;
    for (int ic = 0; ic < 32; ++ic) {
        #pragma unroll
        for (int ky = 0; ky < 3; ++ky) {
            float xv[5];
            #pragma unroll
            for (int i = 0; i < 5; ++i) {
                int ix = oxg * 4 + i;
                xv[i] = (ix < 32) ? in_s[ic][ky][ix] : 0.f;
            }
            #pragma unroll
            for (int kx = 0; kx < 3; ++kx) {
                int R = ic * 9 + ky * 3 + kx;
                float wv = w_s[R * 32 + (oc ^ (R & 31))];
                acc0 += wv * xv[kx];
                acc1 += wv * xv[2 + kx];
            }
        }
    }
    float ps = fmaxf(acc0, 0.f) + fmaxf(acc1, 0.f);
    ps += __shfl_xor(ps, 32);
    if ((t & 32) == 0) atomicAdd(&gsum2[b * 64 + ocg * 32 + oc], ps);
}

// ---------------- eval FUSED: policy/top-5 + gather-resize + conv1 MFMA (to LDS tile)
//                  + conv2 MFMA + relu/mean -> gsum[B,128]
// grid (14 oyT, 4 oxT, 16 b), 256 thr. Replaces conv1_fused + conv2_mfma; g1cl gone.
__global__ __launch_bounds__(256) void eval_fused(const float* __restrict__ ff224,
                                                  const float* __restrict__ gsum2,
                                                  const float* __restrict__ pol_w,
                                                  const float* __restrict__ pol_b,
                                                  const unsigned short* __restrict__ wpk1,
                                                  const unsigned short* __restrict__ wpk,
                                                  float* __restrict__ gsum) {
    int oyT = blockIdx.x;            // 0..13 -> iy0 = oyT*8 (112-res)
    int oxT = blockIdx.y;            // 0..3  -> ix0 = oxT*32
    int b = blockIdx.z;
    int t = threadIdx.x;
    int w = t >> 6;                  // wave id 0..3
    int lane = t & 63;
    int col = lane & 15;
    int kq = lane >> 4;

    __shared__ float fea[64];
    __shared__ float logits[TT];
    __shared__ unsigned char insel[TT];
    __shared__ int sidx[NSEL];
    __shared__ unsigned short res_s[3][19][72];   // 224-res resized rows 16oyT..+18, cols 64oxT..+68
    __shared__ unsigned short tile[9 * 34 * 64];  // conv1 output, swizzled (same layout as R18)

    // --- phase 0: policy + parallel-rank top-5 (exact top_k tie semantics)
    if (t < 64) fea[t] = fmaxf(gsum2[b * 64 + t] * (1.f / 256.f), 0.f);
    __syncthreads();
    if (t < TT) {
        float l = pol_b[t];
        for (int cc = 0; cc < 64; ++cc) l += fea[cc] * pol_w[cc * TT + t];
        logits[t] = l;
    }
    __syncthreads();
    if (t < TT) {
        float li = logits[t];
        int rank = 0;
        for (int j = 0; j < TT; ++j) {
            float lj = logits[j];
            rank += (lj > li) || (lj == li && j < t);
        }
        insel[t] = (rank < NSEL) ? 1 : 0;
    }
    __syncthreads();
    if (t < TT && insel[t]) {
        int pos = 0;
        for (int j = 0; j < t; ++j) pos += insel[j];
        sidx[pos] = t;
    }
    __syncthreads();

    // --- phase 1: gather + resize into res_s (bf16), 3ch x 19 rows x 18 col-groups of 4
    int r0 = oyT * 16;               // 224-res base row
    int c0 = oxT * 64;               // 224-res base col
    for (int u = t; u < 1026; u += 256) {
        int g = u % 18; int tmp = u / 18;
        int rr = tmp % 19; int ch = tmp / 19;
        int row = r0 + rr;
        int cb = c0 + g * 4;
        ushort4 v4 = {0, 0, 0, 0};
        if (row < 224 && cb + 3 < 224) {
            float sample = 5.f * (float)row + 2.f;
            int j0 = 5 * row - 3;
            float ax = 0.f, ay = 0.f, az = 0.f, aw = 0.f, wsum = 0.f;
            #pragma unroll
            for (int dj = 0; dj < 11; ++dj) {
                int j = j0 + dj;
                float wt = (j >= 0 && j < NSEL * 224)
                               ? fmaxf(0.f, 1.f - fabsf(sample - (float)j) * 0.2f) : 0.f;
                int jc = min(max(j, 0), NSEL * 224 - 1);
                int s = jc / 224, y = jc % 224;
                int tf = sidx[s];
                const float4 v = *(const float4*)&ff224[((size_t)((b * TT + tf) * 3 + ch) * 224 + y) * 224 + cb];
                ax += wt * v.x; ay += wt * v.y; az += wt * v.z; aw += wt * v.w;
                wsum += wt;
            }
            float inv = 1.f / wsum;
            v4.x = f2bf(ax * inv); v4.y = f2bf(ay * inv);
            v4.z = f2bf(az * inv); v4.w = f2bf(aw * inv);
        }
        *(ushort4*)&res_s[ch][rr][g * 4] = v4;
    }
    __syncthreads();

    // --- phase 2: conv1 MFMA -> tile (swizzled). 306 px (9x34), 64 oc; wave does 5 groups of 16 px.
    int iy0 = oyT * 8, ix0 = oxT * 32;
    {
        short8_t a1f[4];
        #pragma unroll
        for (int af = 0; af < 4; ++af)
            a1f[af] = *(const short8_t*)&wpk1[((af << 6) + lane) << 3];

        #pragma unroll 1
        for (int g = w * 5; g < w * 5 + 5; ++g) {
            int px = g * 16 + col;
            int pxc = min(px, 305);
            int r = pxc / 34;
            int c = pxc - r * 34;

            unsigned int bw[4];
            #pragma unroll
            for (int jj = 0; jj < 4; ++jj) {
                unsigned int lo = 0, hi = 0;
                int k0 = (kq << 3) + jj * 2;
                {
                    int k = k0;
                    if (k < 27) {
                        int ic = k / 9, r9 = k - ic * 9;
                        int ky = r9 / 3, kx = r9 - ky * 3;
                        lo = res_s[ic][2 * r + ky][2 * c + kx];
                    }
                }
                {
                    int k = k0 + 1;
                    if (k < 27) {
                        int ic = k / 9, r9 = k - ic * 9;
                        int ky = r9 / 3, kx = r9 - ky * 3;
                        hi = res_s[ic][2 * r + ky][2 * c + kx];
                    }
                }
                bw[jj] = lo | (hi << 16);
            }
            short8_t bv;
            {
                unsigned int* bvp = (unsigned int*)&bv;
                bvp[0] = bw[0]; bvp[1] = bw[1]; bvp[2] = bw[2]; bvp[3] = bw[3];
            }

            f32x4 a4[4];
            #pragma unroll
            for (int af = 0; af < 4; ++af) {
                a4[af] = (f32x4){0.f, 0.f, 0.f, 0.f};
                a4[af] = __builtin_amdgcn_mfma_f32_16x16x32_bf16(a1f[af], bv, a4[af], 0, 0, 0);
            }

            if (px < 306) {
                bool ok = (iy0 + r < 112) && (ix0 + c < 112);
                #pragma unroll
                for (int af = 0; af < 4; ++af) {
                    uint2 pk;
                    if (ok) {
                        pk.x = f2bf(fmaxf(a4[af][0], 0.f)) | ((unsigned int)f2bf(fmaxf(a4[af][1], 0.f)) << 16);
                        pk.y = f2bf(fmaxf(a4[af][2], 0.f)) | ((unsigned int)f2bf(fmaxf(a4[af][3], 0.f)) << 16);
                    } else {
                        pk.x = 0; pk.y = 0;
                    }
                    int oc0 = (af << 4) + (kq << 2);
                    int byte = (((px << 6) + oc0) << 1) ^ (((px >> 1) & 7) << 4);
                    *(uint2*)((char*)tile + byte) = pk;
                }
            }
        }
    }
    __syncthreads();

    // --- phase 3: conv2 MFMA over tile (unchanged from R18) + relu/mean epilogue
    int wv = w;
    f32x4 acc[2][4];
    #pragma unroll
    for (int a = 0; a < 2; ++a)
        #pragma unroll
        for (int n = 0; n < 4; ++n)
            acc[a][n] = (f32x4){0.f, 0.f, 0.f, 0.f};

    #pragma unroll 1
    for (int tap = 0; tap < 9; ++tap) {
        const int ky = tap / 3;
        const int kx = tap - ky * 3;
        const int rxl = 2 * col + kx;
        #pragma unroll
        for (int h = 0; h < 2; ++h) {
            const unsigned short* wp = wpk + ((size_t)(((tap * 2 + h) * 8) + (wv << 1)) * 64 + lane) * 8;
            short8_t a0 = *(const short8_t*)wp;
            short8_t a1 = *(const short8_t*)(wp + 512);
            const int e = (h << 5) + (kq << 3);
            #pragma unroll
            for (int nf = 0; nf < 4; ++nf) {
                int r = (2 * nf + ky) * 34 + rxl;
                int byte = (((r << 6) + e) << 1) ^ (((r >> 1) & 7) << 4);
                short8_t bv = *(const short8_t*)((const char*)tile + byte);
                acc[0][nf] = __builtin_amdgcn_mfma_f32_16x16x32_bf16(a0, bv, acc[0][nf], 0, 0, 0);
                acc[1][nf] = __builtin_amdgcn_mfma_f32_16x16x32_bf16(a1, bv, acc[1][nf], 0, 0, 0);
            }
        }
    }

    #pragma unroll
    for (int a = 0; a < 2; ++a) {
        float s0 = 0.f, s1 = 0.f, s2 = 0.f, s3 = 0.f;
        #pragma unroll
        for (int nf = 0; nf < 4; ++nf) {
            s0 += fmaxf(acc[a][nf][0], 0.f);
            s1 += fmaxf(acc[a][nf][1], 0.f);
            s2 += fmaxf(acc[a][nf][2], 0.f);
            s3 += fmaxf(acc[a][nf][3], 0.f);
        }
        #pragma unroll
        for (int off = 1; off < 16; off <<= 1) {
            s0 += __shfl_xor(s0, off);
            s1 += __shfl_xor(s1, off);
            s2 += __shfl_xor(s2, off);
            s3 += __shfl_xor(s3, off);
        }
        if (col == 0) {
            int ocb = wv * 32 + a * 16 + kq * 4;
            atomicAdd(&gsum[b * 128 + ocb + 0], s0);
            atomicAdd(&gsum[b * 128 + ocb + 1], s1);
            atomicAdd(&gsum[b * 128 + ocb + 2], s2);
            atomicAdd(&gsum[b * 128 + ocb + 3], s3);
        }
    }
}

// ---------------- final FC: mean = gsum/3136 ; [B,128] @ [128,10] + b
__global__ void fc_kernel(const float* __restrict__ gsum, const float* __restrict__ fcw,
                          const float* __restrict__ fcb, float* __restrict__ out) {
    int gid = blockIdx.x * blockDim.x + threadIdx.x;
    if (gid >= BB * NCLS) return;
    int cls = gid % NCLS, b = gid / NCLS;
    float s = 0.f;
    for (int c = 0; c < 128; ++c) s += gsum[b * 128 + c] * fcw[c * NCLS + cls];
    out[gid] = fcb[cls] + s * (1.f / 3136.f);
}

extern "C" void kernel_launch(void* const* d_in, const int* in_sizes, int n_in,
                              void* d_out, int out_size, void* d_ws, size_t ws_size,
                              hipStream_t stream) {
    const float* ff64  = (const float*)d_in[0];
    const float* ff224 = (const float*)d_in[1];
    const float* sw1   = (const float*)d_in[2];
    const float* sw2   = (const float*)d_in[3];
    const float* polw  = (const float*)d_in[4];
    const float* polb  = (const float*)d_in[5];
    const float* ew1   = (const float*)d_in[6];
    const float* ew2   = (const float*)d_in[7];
    const float* fcw   = (const float*)d_in[8];
    const float* fcb   = (const float*)d_in[9];
    float* out = (float*)d_out;

    float* ws = (float*)d_ws;
    float* skim_res = ws;                       // 196608 f
    float* gsum2 = skim_res + 196608;           // 1024 f
    float* gsum = gsum2 + 1024;                 // 2048 f
    unsigned short* wpk  = (unsigned short*)(gsum + 2048);  // 73728 bf16
    unsigned short* wpk1 = wpk + 73728;         // 2048 bf16

    // 1. skim resize (float4) + weight pack + zero accumulators
    prep_all<<<480, 256, 0, stream>>>(ff64, ew2, ew1, skim_res, wpk, wpk1, gsum, gsum2);

    // 2. skim conv1+conv2 fused (exact fp32) -> gsum2
    sconv_fused<<<dim3(16, 2, BB), 256, 0, stream>>>(skim_res, sw1, sw2, gsum2);

    // 3. eval FUSED: policy/top-5 + gather-resize + conv1 MFMA + conv2 MFMA + relu/mean
    eval_fused<<<dim3(14, 4, BB), 256, 0, stream>>>(ff224, gsum2, polw, polb, wpk1, wpk, gsum);

    // 4. final FC
    fc_kernel<<<1, 256, 0, stream>>>(gsum, fcw, fcb, out);
}

// Round 20
// 89.403 us; speedup vs baseline: 1.1923x; 1.0852x over previous
//
#include <hip/hip_runtime.h>

#define BB 16
#define TT 30
#define NSEL 5
#define NCLS 10

typedef __attribute__((ext_vector_type(8))) short short8_t;
typedef __attribute__((ext_vector_type(4))) float f32x4;

__device__ inline unsigned short f2bf(float x) {
    unsigned int u = __float_as_uint(x);
    unsigned int r = u + 0x7FFFu + ((u >> 16) & 1u);
    return (unsigned short)(r >> 16);
}

// ---------------- prep_all: blocks 0..191 skim resize (float4); 192..479 weight pack + zeroing
__global__ __launch_bounds__(256) void prep_all(const float* __restrict__ ff64,
                                                const float* __restrict__ w2,
                                                const float* __restrict__ w1,
                                                float* __restrict__ skim_res,
                                                unsigned short* __restrict__ wpk,
                                                unsigned short* __restrict__ wpk1,
                                                float* __restrict__ gsum,
                                                float* __restrict__ gsum2) {
    int bid = blockIdx.x;
    int t = threadIdx.x;
    if (bid < 192) {
        int gid = bid * 256 + t;
        int xg = gid & 15;
        int oy = (gid >> 4) & 63;
        int bc = gid >> 10;
        int c = bc % 3, b = bc / 3;
        int ox0 = xg * 4;
        float sample = 30.f * (float)oy + 14.5f;
        int jlo = max(0, 30 * oy - 16);
        int jhi = min(TT * 64 - 1, 30 * oy + 45);
        float ax = 0.f, ay = 0.f, az = 0.f, aw = 0.f, ws = 0.f;
        for (int j = jlo; j <= jhi; ++j) {
            float w = fmaxf(0.f, 1.f - fabsf(sample - (float)j) * (1.f / 30.f));
            int tt = j >> 6, y = j & 63;
            const float4 v = *(const float4*)&ff64[(((b * TT + tt) * 3 + c) << 12) + (y << 6) + ox0];
            ax += w * v.x; ay += w * v.y; az += w * v.z; aw += w * v.w;
            ws += w;
        }
        float inv = 1.f / ws;
        float4 r; r.x = ax * inv; r.y = ay * inv; r.z = az * inv; r.w = aw * inv;
        *(float4*)&skim_res[(((b * 3 + c) << 6) + oy) * 64 + ox0] = r;
    } else {
        int i = (bid - 192) * 256 + t;
        if (i < BB * 128) gsum[i] = 0.f;
        if (i < BB * 64) gsum2[i] = 0.f;
        if (i < 4 * 64 * 8) {
            int j = i & 7;
            int lane = (i >> 3) & 63;
            int af = i >> 9;
            int oc = af * 16 + (lane & 15);
            int k = ((lane >> 4) << 3) + j;
            wpk1[i] = (k < 27) ? f2bf(w1[oc * 27 + k]) : (unsigned short)0;
        }
        if (i < 9 * 2 * 8 * 64 * 8) {
            int j = i & 7;
            int lane = (i >> 3) & 63;
            int af = (i >> 9) & 7;
            int h = (i >> 12) & 1;
            int tap = i >> 13;
            int oc = af * 16 + (lane & 15);
            int ic = h * 32 + ((lane >> 4) << 3) + j;
            int ky = tap / 3, kx = tap % 3;
            wpk[i] = f2bf(w2[((size_t)(oc * 64 + ic)) * 9 + ky * 3 + kx]);
        }
    }
}

// ---------------- skim conv1+conv2 FUSED (exact fp32): skim_res -> gsum2[16,64]
__global__ __launch_bounds__(256) void sconv_fused(const float* __restrict__ skim_res,
                                                   const float* __restrict__ w1,
                                                   const float* __restrict__ w2,
                                                   float* __restrict__ gsum2) {
    int oy = blockIdx.x;
    int ocg = blockIdx.y;
    int b = blockIdx.z;
    int t = threadIdx.x;
    int oc = t & 31;
    int oxg = t >> 5;

    __shared__ float sr_s[3][7][64];
    __shared__ float w1_s[27][32];
    __shared__ float in_s[32][3][32];
    __shared__ float w_s[288 * 32];

    int ry0 = oy * 4;
    for (int u = t; u < 3 * 7 * 64; u += 256) {
        int ix = u & 63;
        int ry = (u >> 6) % 7;
        int ch = u / 448;
        int row = ry0 + ry;
        sr_s[ch][ry][ix] = (row < 64) ? skim_res[(((b * 3 + ch) << 6) + row) * 64 + ix] : 0.f;
    }
    for (int u = t; u < 864; u += 256) {
        int o = u & 31;
        int k = u >> 5;
        w1_s[k][o] = w1[o * 27 + k];
    }
    for (int u = t; u < 9216; u += 256) {
        int ocl = u / 288;
        int rem = u - ocl * 288;
        w_s[rem * 32 + (ocl ^ (rem & 31))] = w2[(ocg * 32 + ocl) * 288 + rem];
    }
    __syncthreads();

    for (int u = t; u < 32 * 3 * 32; u += 256) {
        int ix = u & 31;
        int ry = (u >> 5) % 3;
        int o1 = u / 96;
        int iy1 = 2 * oy + ry;
        float v = 0.f;
        if (iy1 < 32) {
            float acc = 0.f;
            #pragma unroll
            for (int ch = 0; ch < 3; ++ch) {
                #pragma unroll
                for (int ky = 0; ky < 3; ++ky) {
                    int lr = 2 * ry + ky;
                    #pragma unroll
                    for (int kx = 0; kx < 3; ++kx) {
                        int col = 2 * ix + kx;
                        float x = (col < 64) ? sr_s[ch][lr][col] : 0.f;
                        acc += w1_s[ch * 9 + ky * 3 + kx][o1] * x;
                    }
                }
            }
            v = fmaxf(acc, 0.f);
        }
        in_s[o1][ry][ix] = v;
    }
    __syncthreads();

    float acc0 = 0.f, acc1 = 0.f;
    for (int ic = 0; ic < 32; ++ic) {
        #pragma unroll
        for (int ky = 0; ky < 3; ++ky) {
            float xv[5];
            #pragma unroll
            for (int i = 0; i < 5; ++i) {
                int ix = oxg * 4 + i;
                xv[i] = (ix < 32) ? in_s[ic][ky][ix] : 0.f;
            }
            #pragma unroll
            for (int kx = 0; kx < 3; ++kx) {
                int R = ic * 9 + ky * 3 + kx;
                float wv = w_s[R * 32 + (oc ^ (R & 31))];
                acc0 += wv * xv[kx];
                acc1 += wv * xv[2 + kx];
            }
        }
    }
    float ps = fmaxf(acc0, 0.f) + fmaxf(acc1, 0.f);
    ps += __shfl_xor(ps, 32);
    if ((t & 32) == 0) atomicAdd(&gsum2[b * 64 + ocg * 32 + oc], ps);
}

// ---------------- eval FUSED: policy/top-5 + gather-resize + conv1 MFMA (to LDS tile)
//                  + conv2 MFMA + relu/mean -> gsum[B,128]
// XCD-aware block remap: b = 2*(lin%8) + (lin/8)%2 -> each XCD serves 2 batches,
// so its L2 holds only those batches' gathered frames (~7 MB, L2-resident).
__global__ __launch_bounds__(256) void eval_fused(const float* __restrict__ ff224,
                                                  const float* __restrict__ gsum2,
                                                  const float* __restrict__ pol_w,
                                                  const float* __restrict__ pol_b,
                                                  const unsigned short* __restrict__ wpk1,
                                                  const unsigned short* __restrict__ wpk,
                                                  float* __restrict__ gsum) {
    int lin = blockIdx.x + 14 * (blockIdx.y + 4 * blockIdx.z);
    int b = 2 * (lin & 7) + ((lin >> 3) & 1);
    int tileId = lin >> 4;           // 0..55
    int oyT = tileId / 4;            // 0..13
    int oxT = tileId & 3;            // 0..3
    int t = threadIdx.x;
    int w = t >> 6;                  // wave id 0..3
    int lane = t & 63;
    int col = lane & 15;
    int kq = lane >> 4;

    __shared__ float fea[64];
    __shared__ float logits[TT];
    __shared__ unsigned char insel[TT];
    __shared__ int sidx[NSEL];
    __shared__ unsigned short res_s[3][19][72];
    __shared__ unsigned short tile[9 * 34 * 64];

    // --- phase 0: policy + parallel-rank top-5
    if (t < 64) fea[t] = fmaxf(gsum2[b * 64 + t] * (1.f / 256.f), 0.f);
    __syncthreads();
    if (t < TT) {
        float l = pol_b[t];
        for (int cc = 0; cc < 64; ++cc) l += fea[cc] * pol_w[cc * TT + t];
        logits[t] = l;
    }
    __syncthreads();
    if (t < TT) {
        float li = logits[t];
        int rank = 0;
        for (int j = 0; j < TT; ++j) {
            float lj = logits[j];
            rank += (lj > li) || (lj == li && j < t);
        }
        insel[t] = (rank < NSEL) ? 1 : 0;
    }
    __syncthreads();
    if (t < TT && insel[t]) {
        int pos = 0;
        for (int j = 0; j < t; ++j) pos += insel[j];
        sidx[pos] = t;
    }
    __syncthreads();

    // --- phase 1: gather + resize into res_s (bf16)
    int r0 = oyT * 16;
    int c0 = oxT * 64;
    for (int u = t; u < 1026; u += 256) {
        int g = u % 18; int tmp = u / 18;
        int rr = tmp % 19; int ch = tmp / 19;
        int row = r0 + rr;
        int cb = c0 + g * 4;
        ushort4 v4 = {0, 0, 0, 0};
        if (row < 224 && cb + 3 < 224) {
            float sample = 5.f * (float)row + 2.f;
            int j0 = 5 * row - 3;
            float ax = 0.f, ay = 0.f, az = 0.f, aw = 0.f, wsum = 0.f;
            #pragma unroll
            for (int dj = 0; dj < 11; ++dj) {
                int j = j0 + dj;
                float wt = (j >= 0 && j < NSEL * 224)
                               ? fmaxf(0.f, 1.f - fabsf(sample - (float)j) * 0.2f) : 0.f;
                int jc = min(max(j, 0), NSEL * 224 - 1);
                int s = jc / 224, y = jc % 224;
                int tf = sidx[s];
                const float4 v = *(const float4*)&ff224[((size_t)((b * TT + tf) * 3 + ch) * 224 + y) * 224 + cb];
                ax += wt * v.x; ay += wt * v.y; az += wt * v.z; aw += wt * v.w;
                wsum += wt;
            }
            float inv = 1.f / wsum;
            v4.x = f2bf(ax * inv); v4.y = f2bf(ay * inv);
            v4.z = f2bf(az * inv); v4.w = f2bf(aw * inv);
        }
        *(ushort4*)&res_s[ch][rr][g * 4] = v4;
    }
    __syncthreads();

    // --- phase 2: conv1 MFMA -> tile (swizzled)
    int iy0 = oyT * 8, ix0 = oxT * 32;
    {
        short8_t a1f[4];
        #pragma unroll
        for (int af = 0; af < 4; ++af)
            a1f[af] = *(const short8_t*)&wpk1[((af << 6) + lane) << 3];

        #pragma unroll 1
        for (int g = w * 5; g < w * 5 + 5; ++g) {
            int px = g * 16 + col;
            int pxc = min(px, 305);
            int r = pxc / 34;
            int c = pxc - r * 34;

            unsigned int bw[4];
            #pragma unroll
            for (int jj = 0; jj < 4; ++jj) {
                unsigned int lo = 0, hi = 0;
                int k0 = (kq << 3) + jj * 2;
                {
                    int k = k0;
                    if (k < 27) {
                        int ic = k / 9, r9 = k - ic * 9;
                        int ky = r9 / 3, kx = r9 - ky * 3;
                        lo = res_s[ic][2 * r + ky][2 * c + kx];
                    }
                }
                {
                    int k = k0 + 1;
                    if (k < 27) {
                        int ic = k / 9, r9 = k - ic * 9;
                        int ky = r9 / 3, kx = r9 - ky * 3;
                        hi = res_s[ic][2 * r + ky][2 * c + kx];
                    }
                }
                bw[jj] = lo | (hi << 16);
            }
            short8_t bv;
            {
                unsigned int* bvp = (unsigned int*)&bv;
                bvp[0] = bw[0]; bvp[1] = bw[1]; bvp[2] = bw[2]; bvp[3] = bw[3];
            }

            f32x4 a4[4];
            #pragma unroll
            for (int af = 0; af < 4; ++af) {
                a4[af] = (f32x4){0.f, 0.f, 0.f, 0.f};
                a4[af] = __builtin_amdgcn_mfma_f32_16x16x32_bf16(a1f[af], bv, a4[af], 0, 0, 0);
            }

            if (px < 306) {
                bool ok = (iy0 + r < 112) && (ix0 + c < 112);
                #pragma unroll
                for (int af = 0; af < 4; ++af) {
                    uint2 pk;
                    if (ok) {
                        pk.x = f2bf(fmaxf(a4[af][0], 0.f)) | ((unsigned int)f2bf(fmaxf(a4[af][1], 0.f)) << 16);
                        pk.y = f2bf(fmaxf(a4[af][2], 0.f)) | ((unsigned int)f2bf(fmaxf(a4[af][3], 0.f)) << 16);
                    } else {
                        pk.x = 0; pk.y = 0;
                    }
                    int oc0 = (af << 4) + (kq << 2);
                    int byte = (((px << 6) + oc0) << 1) ^ (((px >> 1) & 7) << 4);
                    *(uint2*)((char*)tile + byte) = pk;
                }
            }
        }
    }
    __syncthreads();

    // --- phase 3: conv2 MFMA over tile + relu/mean epilogue
    int wv = w;
    f32x4 acc[2][4];
    #pragma unroll
    for (int a = 0; a < 2; ++a)
        #pragma unroll
        for (int n = 0; n < 4; ++n)
            acc[a][n] = (f32x4){0.f, 0.f, 0.f, 0.f};

    #pragma unroll 1
    for (int tap = 0; tap < 9; ++tap) {
        const int ky = tap / 3;
        const int kx = tap - ky * 3;
        const int rxl = 2 * col + kx;
        #pragma unroll
        for (int h = 0; h < 2; ++h) {
            const unsigned short* wp = wpk + ((size_t)(((tap * 2 + h) * 8) + (wv << 1)) * 64 + lane) * 8;
            short8_t a0 = *(const short8_t*)wp;
            short8_t a1 = *(const short8_t*)(wp + 512);
            const int e = (h << 5) + (kq << 3);
            #pragma unroll
            for (int nf = 0; nf < 4; ++nf) {
                int r = (2 * nf + ky) * 34 + rxl;
                int byte = (((r << 6) + e) << 1) ^ (((r >> 1) & 7) << 4);
                short8_t bv = *(const short8_t*)((const char*)tile + byte);
                acc[0][nf] = __builtin_amdgcn_mfma_f32_16x16x32_bf16(a0, bv, acc[0][nf], 0, 0, 0);
                acc[1][nf] = __builtin_amdgcn_mfma_f32_16x16x32_bf16(a1, bv, acc[1][nf], 0, 0, 0);
            }
        }
    }

    #pragma unroll
    for (int a = 0; a < 2; ++a) {
        float s0 = 0.f, s1 = 0.f, s2 = 0.f, s3 = 0.f;
        #pragma unroll
        for (int nf = 0; nf < 4; ++nf) {
            s0 += fmaxf(acc[a][nf][0], 0.f);
            s1 += fmaxf(acc[a][nf][1], 0.f);
            s2 += fmaxf(acc[a][nf][2], 0.f);
            s3 += fmaxf(acc[a][nf][3], 0.f);
        }
        #pragma unroll
        for (int off = 1; off < 16; off <<= 1) {
            s0 += __shfl_xor(s0, off);
            s1 += __shfl_xor(s1, off);
            s2 += __shfl_xor(s2, off);
            s3 += __shfl_xor(s3, off);
        }
        if (col == 0) {
            int ocb = wv * 32 + a * 16 + kq * 4;
            atomicAdd(&gsum[b * 128 + ocb + 0], s0);
            atomicAdd(&gsum[b * 128 + ocb + 1], s1);
            atomicAdd(&gsum[b * 128 + ocb + 2], s2);
            atomicAdd(&gsum[b * 128 + ocb + 3], s3);
        }
    }
}

// ---------------- final FC: mean = gsum/3136 ; [B,128] @ [128,10] + b
__global__ void fc_kernel(const float* __restrict__ gsum, const float* __restrict__ fcw,
                          const float* __restrict__ fcb, float* __restrict__ out) {
    int gid = blockIdx.x * blockDim.x + threadIdx.x;
    if (gid >= BB * NCLS) return;
    int cls = gid % NCLS, b = gid / NCLS;
    float s = 0.f;
    for (int c = 0; c < 128; ++c) s += gsum[b * 128 + c] * fcw[c * NCLS + cls];
    out[gid] = fcb[cls] + s * (1.f / 3136.f);
}

extern "C" void kernel_launch(void* const* d_in, const int* in_sizes, int n_in,
                              void* d_out, int out_size, void* d_ws, size_t ws_size,
                              hipStream_t stream) {
    const float* ff64  = (const float*)d_in[0];
    const float* ff224 = (const float*)d_in[1];
    const float* sw1   = (const float*)d_in[2];
    const float* sw2   = (const float*)d_in[3];
    const float* polw  = (const float*)d_in[4];
    const float* polb  = (const float*)d_in[5];
    const float* ew1   = (const float*)d_in[6];
    const float* ew2   = (const float*)d_in[7];
    const float* fcw   = (const float*)d_in[8];
    const float* fcb   = (const float*)d_in[9];
    float* out = (float*)d_out;

    float* ws = (float*)d_ws;
    float* skim_res = ws;                       // 196608 f
    float* gsum2 = skim_res + 196608;           // 1024 f
    float* gsum = gsum2 + 1024;                 // 2048 f
    unsigned short* wpk  = (unsigned short*)(gsum + 2048);  // 73728 bf16
    unsigned short* wpk1 = wpk + 73728;         // 2048 bf16

    // 1. skim resize (float4) + weight pack + zero accumulators
    prep_all<<<480, 256, 0, stream>>>(ff64, ew2, ew1, skim_res, wpk, wpk1, gsum, gsum2);

    // 2. skim conv1+conv2 fused (exact fp32) -> gsum2
    sconv_fused<<<dim3(16, 2, BB), 256, 0, stream>>>(skim_res, sw1, sw2, gsum2);

    // 3. eval FUSED (XCD-aware batch mapping): policy/top-5 + gather-resize + conv1 + conv2 + mean
    eval_fused<<<dim3(14, 4, BB), 256, 0, stream>>>(ff224, gsum2, polw, polb, wpk1, wpk, gsum);

    // 4. final FC
    fc_kernel<<<1, 256, 0, stream>>>(gsum, fcw, fcb, out);
}

// Round 21
// 88.993 us; speedup vs baseline: 1.1978x; 1.0046x over previous
//
#include <hip/hip_runtime.h>

#define BB 16
#define TT 30
#define NSEL 5
#define NCLS 10

typedef __attribute__((ext_vector_type(8))) short short8_t;
typedef __attribute__((ext_vector_type(4))) float f32x4;

__device__ inline unsigned short f2bf(float x) {
    unsigned int u = __float_as_uint(x);
    unsigned int r = u + 0x7FFFu + ((u >> 16) & 1u);
    return (unsigned short)(r >> 16);
}

// ---------------- prep_all: blocks 0..191 skim resize (float4); 192..479 weight pack + zeroing
__global__ __launch_bounds__(256) void prep_all(const float* __restrict__ ff64,
                                                const float* __restrict__ w2,
                                                const float* __restrict__ w1,
                                                float* __restrict__ skim_res,
                                                unsigned short* __restrict__ wpk,
                                                unsigned short* __restrict__ wpk1,
                                                float* __restrict__ gsum,
                                                float* __restrict__ gsum2) {
    int bid = blockIdx.x;
    int t = threadIdx.x;
    if (bid < 192) {
        int gid = bid * 256 + t;
        int xg = gid & 15;
        int oy = (gid >> 4) & 63;
        int bc = gid >> 10;
        int c = bc % 3, b = bc / 3;
        int ox0 = xg * 4;
        float sample = 30.f * (float)oy + 14.5f;
        int jlo = max(0, 30 * oy - 16);
        int jhi = min(TT * 64 - 1, 30 * oy + 45);
        float ax = 0.f, ay = 0.f, az = 0.f, aw = 0.f, ws = 0.f;
        for (int j = jlo; j <= jhi; ++j) {
            float w = fmaxf(0.f, 1.f - fabsf(sample - (float)j) * (1.f / 30.f));
            int tt = j >> 6, y = j & 63;
            const float4 v = *(const float4*)&ff64[(((b * TT + tt) * 3 + c) << 12) + (y << 6) + ox0];
            ax += w * v.x; ay += w * v.y; az += w * v.z; aw += w * v.w;
            ws += w;
        }
        float inv = 1.f / ws;
        float4 r; r.x = ax * inv; r.y = ay * inv; r.z = az * inv; r.w = aw * inv;
        *(float4*)&skim_res[(((b * 3 + c) << 6) + oy) * 64 + ox0] = r;
    } else {
        int i = (bid - 192) * 256 + t;
        if (i < BB * 128) gsum[i] = 0.f;
        if (i < BB * 64) gsum2[i] = 0.f;
        if (i < 4 * 64 * 8) {
            int j = i & 7;
            int lane = (i >> 3) & 63;
            int af = i >> 9;
            int oc = af * 16 + (lane & 15);
            int k = ((lane >> 4) << 3) + j;
            wpk1[i] = (k < 27) ? f2bf(w1[oc * 27 + k]) : (unsigned short)0;
        }
        if (i < 9 * 2 * 8 * 64 * 8) {
            int j = i & 7;
            int lane = (i >> 3) & 63;
            int af = (i >> 9) & 7;
            int h = (i >> 12) & 1;
            int tap = i >> 13;
            int oc = af * 16 + (lane & 15);
            int ic = h * 32 + ((lane >> 4) << 3) + j;
            int ky = tap / 3, kx = tap % 3;
            wpk[i] = f2bf(w2[((size_t)(oc * 64 + ic)) * 9 + ky * 3 + kx]);
        }
    }
}

// ---------------- skim conv1+conv2 FUSED (exact fp32): skim_res -> gsum2[16,64]
__global__ __launch_bounds__(256) void sconv_fused(const float* __restrict__ skim_res,
                                                   const float* __restrict__ w1,
                                                   const float* __restrict__ w2,
                                                   float* __restrict__ gsum2) {
    int oy = blockIdx.x;
    int ocg = blockIdx.y;
    int b = blockIdx.z;
    int t = threadIdx.x;
    int oc = t & 31;
    int oxg = t >> 5;

    __shared__ float sr_s[3][7][64];
    __shared__ float w1_s[27][32];
    __shared__ float in_s[32][3][32];
    __shared__ float w_s[288 * 32];

    int ry0 = oy * 4;
    for (int u = t; u < 3 * 7 * 64; u += 256) {
        int ix = u & 63;
        int ry = (u >> 6) % 7;
        int ch = u / 448;
        int row = ry0 + ry;
        sr_s[ch][ry][ix] = (row < 64) ? skim_res[(((b * 3 + ch) << 6) + row) * 64 + ix] : 0.f;
    }
    for (int u = t; u < 864; u += 256) {
        int o = u & 31;
        int k = u >> 5;
        w1_s[k][o] = w1[o * 27 + k];
    }
    for (int u = t; u < 9216; u += 256) {
        int ocl = u / 288;
        int rem = u - ocl * 288;
        w_s[rem * 32 + (ocl ^ (rem & 31))] = w2[(ocg * 32 + ocl) * 288 + rem];
    }
    __syncthreads();

    for (int u = t; u < 32 * 3 * 32; u += 256) {
        int ix = u & 31;
        int ry = (u >> 5) % 3;
        int o1 = u / 96;
        int iy1 = 2 * oy + ry;
        float v = 0.f;
        if (iy1 < 32) {
            float acc = 0.f;
            #pragma unroll
            for (int ch = 0; ch < 3; ++ch) {
                #pragma unroll
                for (int ky = 0; ky < 3; ++ky) {
                    int lr = 2 * ry + ky;
                    #pragma unroll
                    for (int kx = 0; kx < 3; ++kx) {
                        int col = 2 * ix + kx;
                        float x = (col < 64) ? sr_s[ch][lr][col] : 0.f;
                        acc += w1_s[ch * 9 + ky * 3 + kx][o1] * x;
                    }
                }
            }
            v = fmaxf(acc, 0.f);
        }
        in_s[o1][ry][ix] = v;
    }
    __syncthreads();

    float acc0 = 0.f, acc1 = 0.f;
    for (int ic = 0; ic < 32; ++ic) {
        #pragma unroll
        for (int ky = 0; ky < 3; ++ky) {
            float xv[5];
            #pragma unroll
            for (int i = 0; i < 5; ++i) {
                int ix = oxg * 4 + i;
                xv[i] = (ix < 32) ? in_s[ic][ky][ix] : 0.f;
            }
            #pragma unroll
            for (int kx = 0; kx < 3; ++kx) {
                int R = ic * 9 + ky * 3 + kx;
                float wv = w_s[R * 32 + (oc ^ (R & 31))];
                acc0 += wv * xv[kx];
                acc1 += wv * xv[2 + kx];
            }
        }
    }
    float ps = fmaxf(acc0, 0.f) + fmaxf(acc1, 0.f);
    ps += __shfl_xor(ps, 32);
    if ((t & 32) == 0) atomicAdd(&gsum2[b * 64 + ocg * 32 + oc], ps);
}

// ---------------- eval FUSED: policy/top-5 + gather-resize + conv1 MFMA (to LDS tile)
//                  + conv2 MFMA + relu/mean -> gsum[B,128]
// XCD-aware batch mapping; gather uses 9 taps (dj=1..9): taps 0 and 10 have weight
// exactly 0 (|sample-j|=5), so dropping them is bit-identical.
__global__ __launch_bounds__(256) void eval_fused(const float* __restrict__ ff224,
                                                  const float* __restrict__ gsum2,
                                                  const float* __restrict__ pol_w,
                                                  const float* __restrict__ pol_b,
                                                  const unsigned short* __restrict__ wpk1,
                                                  const unsigned short* __restrict__ wpk,
                                                  float* __restrict__ gsum) {
    int lin = blockIdx.x + 14 * (blockIdx.y + 4 * blockIdx.z);
    int b = 2 * (lin & 7) + ((lin >> 3) & 1);
    int tileId = lin >> 4;           // 0..55
    int oyT = tileId / 4;            // 0..13
    int oxT = tileId & 3;            // 0..3
    int t = threadIdx.x;
    int w = t >> 6;                  // wave id 0..3
    int lane = t & 63;
    int col = lane & 15;
    int kq = lane >> 4;

    __shared__ float fea[64];
    __shared__ float logits[TT];
    __shared__ unsigned char insel[TT];
    __shared__ int sidx[NSEL];
    __shared__ unsigned short res_s[3][19][72];
    __shared__ unsigned short tile[9 * 34 * 64];

    // --- phase 0: policy + parallel-rank top-5
    if (t < 64) fea[t] = fmaxf(gsum2[b * 64 + t] * (1.f / 256.f), 0.f);
    __syncthreads();
    if (t < TT) {
        float l = pol_b[t];
        for (int cc = 0; cc < 64; ++cc) l += fea[cc] * pol_w[cc * TT + t];
        logits[t] = l;
    }
    __syncthreads();
    if (t < TT) {
        float li = logits[t];
        int rank = 0;
        for (int j = 0; j < TT; ++j) {
            float lj = logits[j];
            rank += (lj > li) || (lj == li && j < t);
        }
        insel[t] = (rank < NSEL) ? 1 : 0;
    }
    __syncthreads();
    if (t < TT && insel[t]) {
        int pos = 0;
        for (int j = 0; j < t; ++j) pos += insel[j];
        sidx[pos] = t;
    }
    __syncthreads();

    // --- phase 1: gather + resize into res_s (bf16), 9 nonzero taps
    int r0 = oyT * 16;
    int c0 = oxT * 64;
    for (int u = t; u < 1026; u += 256) {
        int g = u % 18; int tmp = u / 18;
        int rr = tmp % 19; int ch = tmp / 19;
        int row = r0 + rr;
        int cb = c0 + g * 4;
        ushort4 v4 = {0, 0, 0, 0};
        if (row < 224 && cb + 3 < 224) {
            float sample = 5.f * (float)row + 2.f;
            int j0 = 5 * row - 3;
            float ax = 0.f, ay = 0.f, az = 0.f, aw = 0.f, wsum = 0.f;
            #pragma unroll
            for (int dj = 1; dj < 10; ++dj) {
                int j = j0 + dj;
                float wt = (j >= 0 && j < NSEL * 224)
                               ? fmaxf(0.f, 1.f - fabsf(sample - (float)j) * 0.2f) : 0.f;
                int jc = min(max(j, 0), NSEL * 224 - 1);
                int s = jc / 224, y = jc % 224;
                int tf = sidx[s];
                const float4 v = *(const float4*)&ff224[((size_t)((b * TT + tf) * 3 + ch) * 224 + y) * 224 + cb];
                ax += wt * v.x; ay += wt * v.y; az += wt * v.z; aw += wt * v.w;
                wsum += wt;
            }
            float inv = 1.f / wsum;
            v4.x = f2bf(ax * inv); v4.y = f2bf(ay * inv);
            v4.z = f2bf(az * inv); v4.w = f2bf(aw * inv);
        }
        *(ushort4*)&res_s[ch][rr][g * 4] = v4;
    }
    __syncthreads();

    // --- phase 2: conv1 MFMA -> tile (swizzled)
    int iy0 = oyT * 8, ix0 = oxT * 32;
    {
        short8_t a1f[4];
        #pragma unroll
        for (int af = 0; af < 4; ++af)
            a1f[af] = *(const short8_t*)&wpk1[((af << 6) + lane) << 3];

        #pragma unroll 1
        for (int g = w * 5; g < w * 5 + 5; ++g) {
            int px = g * 16 + col;
            int pxc = min(px, 305);
            int r = pxc / 34;
            int c = pxc - r * 34;

            unsigned int bw[4];
            #pragma unroll
            for (int jj = 0; jj < 4; ++jj) {
                unsigned int lo = 0, hi = 0;
                int k0 = (kq << 3) + jj * 2;
                {
                    int k = k0;
                    if (k < 27) {
                        int ic = k / 9, r9 = k - ic * 9;
                        int ky = r9 / 3, kx = r9 - ky * 3;
                        lo = res_s[ic][2 * r + ky][2 * c + kx];
                    }
                }
                {
                    int k = k0 + 1;
                    if (k < 27) {
                        int ic = k / 9, r9 = k - ic * 9;
                        int ky = r9 / 3, kx = r9 - ky * 3;
                        hi = res_s[ic][2 * r + ky][2 * c + kx];
                    }
                }
                bw[jj] = lo | (hi << 16);
            }
            short8_t bv;
            {
                unsigned int* bvp = (unsigned int*)&bv;
                bvp[0] = bw[0]; bvp[1] = bw[1]; bvp[2] = bw[2]; bvp[3] = bw[3];
            }

            f32x4 a4[4];
            #pragma unroll
            for (int af = 0; af < 4; ++af) {
                a4[af] = (f32x4){0.f, 0.f, 0.f, 0.f};
                a4[af] = __builtin_amdgcn_mfma_f32_16x16x32_bf16(a1f[af], bv, a4[af], 0, 0, 0);
            }

            if (px < 306) {
                bool ok = (iy0 + r < 112) && (ix0 + c < 112);
                #pragma unroll
                for (int af = 0; af < 4; ++af) {
                    uint2 pk;
                    if (ok) {
                        pk.x = f2bf(fmaxf(a4[af][0], 0.f)) | ((unsigned int)f2bf(fmaxf(a4[af][1], 0.f)) << 16);
                        pk.y = f2bf(fmaxf(a4[af][2], 0.f)) | ((unsigned int)f2bf(fmaxf(a4[af][3], 0.f)) << 16);
                    } else {
                        pk.x = 0; pk.y = 0;
                    }
                    int oc0 = (af << 4) + (kq << 2);
                    int byte = (((px << 6) + oc0) << 1) ^ (((px >> 1) & 7) << 4);
                    *(uint2*)((char*)tile + byte) = pk;
                }
            }
        }
    }
    __syncthreads();

    // --- phase 3: conv2 MFMA over tile + relu/mean epilogue
    int wv = w;
    f32x4 acc[2][4];
    #pragma unroll
    for (int a = 0; a < 2; ++a)
        #pragma unroll
        for (int n = 0; n < 4; ++n)
            acc[a][n] = (f32x4){0.f, 0.f, 0.f, 0.f};

    #pragma unroll 1
    for (int tap = 0; tap < 9; ++tap) {
        const int ky = tap / 3;
        const int kx = tap - ky * 3;
        const int rxl = 2 * col + kx;
        #pragma unroll
        for (int h = 0; h < 2; ++h) {
            const unsigned short* wp = wpk + ((size_t)(((tap * 2 + h) * 8) + (wv << 1)) * 64 + lane) * 8;
            short8_t a0 = *(const short8_t*)wp;
            short8_t a1 = *(const short8_t*)(wp + 512);
            const int e = (h << 5) + (kq << 3);
            #pragma unroll
            for (int nf = 0; nf < 4; ++nf) {
                int r = (2 * nf + ky) * 34 + rxl;
                int byte = (((r << 6) + e) << 1) ^ (((r >> 1) & 7) << 4);
                short8_t bv = *(const short8_t*)((const char*)tile + byte);
                acc[0][nf] = __builtin_amdgcn_mfma_f32_16x16x32_bf16(a0, bv, acc[0][nf], 0, 0, 0);
                acc[1][nf] = __builtin_amdgcn_mfma_f32_16x16x32_bf16(a1, bv, acc[1][nf], 0, 0, 0);
            }
        }
    }

    #pragma unroll
    for (int a = 0; a < 2; ++a) {
        float s0 = 0.f, s1 = 0.f, s2 = 0.f, s3 = 0.f;
        #pragma unroll
        for (int nf = 0; nf < 4; ++nf) {
            s0 += fmaxf(acc[a][nf][0], 0.f);
            s1 += fmaxf(acc[a][nf][1], 0.f);
            s2 += fmaxf(acc[a][nf][2], 0.f);
            s3 += fmaxf(acc[a][nf][3], 0.f);
        }
        #pragma unroll
        for (int off = 1; off < 16; off <<= 1) {
            s0 += __shfl_xor(s0, off);
            s1 += __shfl_xor(s1, off);
            s2 += __shfl_xor(s2, off);
            s3 += __shfl_xor(s3, off);
        }
        if (col == 0) {
            int ocb = wv * 32 + a * 16 + kq * 4;
            atomicAdd(&gsum[b * 128 + ocb + 0], s0);
            atomicAdd(&gsum[b * 128 + ocb + 1], s1);
            atomicAdd(&gsum[b * 128 + ocb + 2], s2);
            atomicAdd(&gsum[b * 128 + ocb + 3], s3);
        }
    }
}

// ---------------- final FC: mean = gsum/3136 ; [B,128] @ [128,10] + b
__global__ void fc_kernel(const float* __restrict__ gsum, const float* __restrict__ fcw,
                          const float* __restrict__ fcb, float* __restrict__ out) {
    int gid = blockIdx.x * blockDim.x + threadIdx.x;
    if (gid >= BB * NCLS) return;
    int cls = gid % NCLS, b = gid / NCLS;
    float s = 0.f;
    for (int c = 0; c < 128; ++c) s += gsum[b * 128 + c] * fcw[c * NCLS + cls];
    out[gid] = fcb[cls] + s * (1.f / 3136.f);
}

extern "C" void kernel_launch(void* const* d_in, const int* in_sizes, int n_in,
                              void* d_out, int out_size, void* d_ws, size_t ws_size,
                              hipStream_t stream) {
    const float* ff64  = (const float*)d_in[0];
    const float* ff224 = (const float*)d_in[1];
    const float* sw1   = (const float*)d_in[2];
    const float* sw2   = (const float*)d_in[3];
    const float* polw  = (const float*)d_in[4];
    const float* polb  = (const float*)d_in[5];
    const float* ew1   = (const float*)d_in[6];
    const float* ew2   = (const float*)d_in[7];
    const float* fcw   = (const float*)d_in[8];
    const float* fcb   = (const float*)d_in[9];
    float* out = (float*)d_out;

    float* ws = (float*)d_ws;
    float* skim_res = ws;                       // 196608 f
    float* gsum2 = skim_res + 196608;           // 1024 f
    float* gsum = gsum2 + 1024;                 // 2048 f
    unsigned short* wpk  = (unsigned short*)(gsum + 2048);  // 73728 bf16
    unsigned short* wpk1 = wpk + 73728;         // 2048 bf16

    // 1. skim resize (float4) + weight pack + zero accumulators
    prep_all<<<480, 256, 0, stream>>>(ff64, ew2, ew1, skim_res, wpk, wpk1, gsum, gsum2);

    // 2. skim conv1+conv2 fused (exact fp32) -> gsum2
    sconv_fused<<<dim3(16, 2, BB), 256, 0, stream>>>(skim_res, sw1, sw2, gsum2);

    // 3. eval FUSED (XCD-aware batch mapping, 9-tap gather)
    eval_fused<<<dim3(14, 4, BB), 256, 0, stream>>>(ff224, gsum2, polw, polb, wpk1, wpk, gsum);

    // 4. final FC
    fc_kernel<<<1, 256, 0, stream>>>(gsum, fcw, fcb, out);
}